// Round 2
// baseline (1910.377 us; speedup 1.0000x reference)
//
#include <hip/hip_runtime.h>
#include <hip/hip_bf16.h>

#define NEG 0.2f

__device__ __forceinline__ float lrelu(float x){ return x > 0.f ? x : NEG * x; }
__device__ __forceinline__ float elu_f(float x){ return x > 0.f ? x : expm1f(x); }
__device__ __forceinline__ unsigned short f2bf(float f){
  unsigned int u = __float_as_uint(f);
  unsigned int r = u + 0x7fffu + ((u >> 16) & 1u);   // round-to-nearest-even
  return (unsigned short)(r >> 16);
}

// ---------------- CSR build ----------------
__global__ void k_count(const int* __restrict__ dst, int E, int* deg){
  int e = blockIdx.x * blockDim.x + threadIdx.x;
  if (e < E) atomicAdd(&deg[dst[e]], 1);
}

__global__ void k_scan1(const int* __restrict__ deg, int* row_ptr, int* partials, int N){
  __shared__ int sd[256];
  int t = threadIdx.x;
  int base = blockIdx.x * 1024 + t * 4;
  int v[4]; int s = 0;
  #pragma unroll
  for (int j = 0; j < 4; j++){ int i = base + j; v[j] = (i < N) ? (deg[i] + 1) : 0; s += v[j]; }
  sd[t] = s; __syncthreads();
  for (int off = 1; off < 256; off <<= 1){
    int x = (t >= off) ? sd[t - off] : 0;
    __syncthreads(); sd[t] += x; __syncthreads();
  }
  int pre = (t > 0) ? sd[t - 1] : 0;
  #pragma unroll
  for (int j = 0; j < 4; j++){ int i = base + j; if (i < N) row_ptr[i] = pre; pre += v[j]; }
  if (t == 255) partials[blockIdx.x] = sd[255];
}

__global__ void k_scan2(int* partials, int NB){
  __shared__ int sd[128];
  int t = threadIdx.x;
  int v = (t < NB) ? partials[t] : 0;
  sd[t] = v; __syncthreads();
  for (int off = 1; off < 128; off <<= 1){
    int x = (t >= off) ? sd[t - off] : 0;
    __syncthreads(); sd[t] += x; __syncthreads();
  }
  if (t < NB) partials[t] = sd[t] - v;   // exclusive
}

__global__ void k_scan3(int* row_ptr, int* cursor, const int* __restrict__ partials, int N, int total){
  int i = blockIdx.x * blockDim.x + threadIdx.x;
  if (i < N){ int r = row_ptr[i] + partials[i >> 10]; row_ptr[i] = r; cursor[i] = r; }
  if (i == 0) row_ptr[N] = total;
}

__global__ void k_scatter(const int* __restrict__ src, const int* __restrict__ dst,
                          int E, int N, int* cursor,
                          int* __restrict__ csr_src, int* __restrict__ csr_dst){
  int e = blockIdx.x * blockDim.x + threadIdx.x;
  int tot = E + N;
  if (e >= tot) return;
  int s, d;
  if (e < E){ s = src[e]; d = dst[e]; } else { s = e - E; d = s; }
  int pos = atomicAdd(&cursor[d], 1);
  csr_src[pos] = s;
  csr_dst[pos] = d;
}

// ---------------- per-edge attention weights ----------------
__global__ void k_w1(const int* __restrict__ csr_src, const int* __restrict__ csr_dst,
                     const float* __restrict__ ss, const float* __restrict__ sd,
                     float* __restrict__ we, int total){
  int e = blockIdx.x * blockDim.x + threadIdx.x;
  if (e >= total) return;
  int s = csr_src[e], d = csr_dst[e];
  float4 a = *(const float4*)&ss[(size_t)s * 4];
  float4 b = *(const float4*)&sd[(size_t)d * 4];
  float4 w;
  w.x = __expf(lrelu(a.x + b.x));
  w.y = __expf(lrelu(a.y + b.y));
  w.z = __expf(lrelu(a.z + b.z));
  w.w = __expf(lrelu(a.w + b.w));
  *(float4*)&we[(size_t)e * 4] = w;
}

__global__ void k_w2(const int* __restrict__ csr_src, const int* __restrict__ csr_dst,
                     const float* __restrict__ ss, const float* __restrict__ sd,
                     float* __restrict__ we, int total){
  int e = blockIdx.x * blockDim.x + threadIdx.x;
  if (e >= total) return;
  int s = csr_src[e], d = csr_dst[e];
  we[e] = __expf(lrelu(ss[s] + sd[d]));
}

// ---------------- GEMM1: x[N,128] @ W[128,128] -> h_bf[N,128] (bf16), + s_src1/s_dst1[N,4]
// block = 256 thr, computes 64 rows x 64 cols (blockIdx.y = column half). LDS 65 KB -> 2 blocks/CU.
__global__ __launch_bounds__(256, 2) void k_gemm1(
    const float* __restrict__ x, const float* __restrict__ W,
    const float* __restrict__ a_src, const float* __restrict__ a_dst,
    unsigned short* __restrict__ h_bf, float* __restrict__ s_src, float* __restrict__ s_dst, int N){
  __shared__ __align__(16) float Wl[128 * 64];
  __shared__ __align__(16) float Xl[64 * 132];
  int t = threadIdx.x;
  int rb = blockIdx.x * 64;
  int ch = blockIdx.y;             // column half

  const float4* Wg4 = (const float4*)W;
  float4* Wl4 = (float4*)Wl;
  #pragma unroll
  for (int j = 0; j < 8; j++){
    int fi = j * 256 + t;          // 0..2047
    int k = fi >> 4, c4 = fi & 15;
    Wl4[fi] = Wg4[k * 32 + ch * 16 + c4];
  }
  #pragma unroll
  for (int j = 0; j < 8; j++){
    int fi = j * 256 + t;          // 0..2047
    int row = fi >> 5, c4 = fi & 31;
    float4 v = make_float4(0.f, 0.f, 0.f, 0.f);
    if (rb + row < N) v = *(const float4*)&x[(size_t)(rb + row) * 128 + c4 * 4];
    *(float4*)&Xl[row * 132 + c4 * 4] = v;
  }
  __syncthreads();

  int cg = t & 15, rg = t >> 4;
  int c0 = cg * 4, r0 = rg * 4;
  float acc[4][4] = {};

  for (int k = 0; k < 128; k += 4){
    float4 a[4];
    #pragma unroll
    for (int i = 0; i < 4; i++) a[i] = *(float4*)&Xl[(r0 + i) * 132 + k];
    #pragma unroll
    for (int kk = 0; kk < 4; kk++){
      float4 b = *(float4*)&Wl[(k + kk) * 64 + c0];
      #pragma unroll
      for (int i = 0; i < 4; i++){
        float av = (kk == 0) ? a[i].x : (kk == 1) ? a[i].y : (kk == 2) ? a[i].z : a[i].w;
        acc[i][0] += av * b.x; acc[i][1] += av * b.y;
        acc[i][2] += av * b.z; acc[i][3] += av * b.w;
      }
    }
  }

  int gc = ch * 64 + c0;           // global column
  int ghead = ch * 2 + (c0 >> 5);  // global head index 0..3
  float as[4], ad[4];
  #pragma unroll
  for (int j = 0; j < 4; j++){ as[j] = a_src[gc + j]; ad[j] = a_dst[gc + j]; }
  #pragma unroll
  for (int i = 0; i < 4; i++){
    int row = rb + r0 + i;
    bool ok = row < N;
    if (ok){
      ushort4 o;
      o.x = f2bf(acc[i][0]); o.y = f2bf(acc[i][1]);
      o.z = f2bf(acc[i][2]); o.w = f2bf(acc[i][3]);
      *(ushort4*)&h_bf[(size_t)row * 128 + gc] = o;
    }
    float ps = acc[i][0]*as[0] + acc[i][1]*as[1] + acc[i][2]*as[2] + acc[i][3]*as[3];
    float pd = acc[i][0]*ad[0] + acc[i][1]*ad[1] + acc[i][2]*ad[2] + acc[i][3]*ad[3];
    ps += __shfl_xor(ps, 1, 8); ps += __shfl_xor(ps, 2, 8); ps += __shfl_xor(ps, 4, 8);
    pd += __shfl_xor(pd, 1, 8); pd += __shfl_xor(pd, 2, 8); pd += __shfl_xor(pd, 4, 8);
    if ((t & 7) == 0 && ok){ s_src[(size_t)row * 4 + ghead] = ps; s_dst[(size_t)row * 4 + ghead] = pd; }
  }
}

// ---------------- agg1: 1 wave per node, bf16x2 gather, x4 unrolled ----------------
__global__ __launch_bounds__(256) void k_agg1(
    const int* __restrict__ row_ptr, const int* __restrict__ csr_src,
    const float* __restrict__ we, const __hip_bfloat162* __restrict__ hb2,
    float* __restrict__ out1, int N){
  int n = blockIdx.x * 4 + (threadIdx.x >> 6);
  if (n >= N) return;
  int l = threadIdx.x & 63;
  int hd = l >> 4;                 // head = channel/32, channels 2l,2l+1
  int beg = row_ptr[n], end = row_ptr[n + 1];
  float ax = 0.f, ay = 0.f, sw = 0.f;
  int e = beg;
  for (; e + 4 <= end; e += 4){
    int s0 = csr_src[e], s1 = csr_src[e+1], s2 = csr_src[e+2], s3 = csr_src[e+3];
    float w0 = we[(size_t)e*4 + hd],     w1 = we[(size_t)e*4 + 4 + hd];
    float w2 = we[(size_t)e*4 + 8 + hd], w3 = we[(size_t)e*4 + 12 + hd];
    float2 v0 = __bfloat1622float2(hb2[(size_t)s0 * 64 + l]);
    float2 v1 = __bfloat1622float2(hb2[(size_t)s1 * 64 + l]);
    float2 v2 = __bfloat1622float2(hb2[(size_t)s2 * 64 + l]);
    float2 v3 = __bfloat1622float2(hb2[(size_t)s3 * 64 + l]);
    ax += w0*v0.x + w1*v1.x + w2*v2.x + w3*v3.x;
    ay += w0*v0.y + w1*v1.y + w2*v2.y + w3*v3.y;
    sw += w0 + w1 + w2 + w3;
  }
  for (; e < end; e++){
    int s = csr_src[e];
    float w = we[(size_t)e*4 + hd];
    float2 v = __bfloat1622float2(hb2[(size_t)s * 64 + l]);
    ax += w*v.x; ay += w*v.y; sw += w;
  }
  float inv = 1.f / (sw + 1e-16f);
  *(float2*)&out1[(size_t)n * 128 + l * 2] = make_float2(ax * inv, ay * inv);
}

// ---------------- GEMM2: elu(out1+b1)[N,128] @ W2[128,32] -> h2[N,32], + s_src2/s_dst2[N] ----------------
__global__ __launch_bounds__(256) void k_gemm2(
    const float* __restrict__ out1, const float* __restrict__ b1,
    const float* __restrict__ W2,
    const float* __restrict__ a_src, const float* __restrict__ a_dst,
    float* __restrict__ h2, float* __restrict__ s_src2, float* __restrict__ s_dst2, int N){
  __shared__ __align__(16) float Wl[128 * 32];
  __shared__ __align__(16) float Xl[64 * 132];
  int t = threadIdx.x;
  int rb = blockIdx.x * 64;

  const float4* Wg4 = (const float4*)W2;
  float4* Wl4 = (float4*)Wl;
  #pragma unroll
  for (int j = 0; j < 4; j++) Wl4[j * 256 + t] = Wg4[j * 256 + t];

  #pragma unroll
  for (int j = 0; j < 8; j++){
    int fi = j * 256 + t;
    int row = fi >> 5; int kc = (fi & 31) * 4;
    float4 v = make_float4(0.f, 0.f, 0.f, 0.f);
    if (rb + row < N){
      float4 xv = *(const float4*)&out1[(size_t)(rb + row) * 128 + kc];
      float4 bv = *(const float4*)&b1[kc];
      v.x = elu_f(xv.x + bv.x); v.y = elu_f(xv.y + bv.y);
      v.z = elu_f(xv.z + bv.z); v.w = elu_f(xv.w + bv.w);
    }
    *(float4*)&Xl[row * 132 + kc] = v;
  }
  __syncthreads();

  int cg = t & 7, rg = t >> 3;
  int c0 = cg * 4, r0 = rg * 2;
  float acc[2][4] = {};

  #pragma unroll 8
  for (int k = 0; k < 128; k++){
    float a0 = Xl[r0 * 132 + k];
    float a1 = Xl[(r0 + 1) * 132 + k];
    float4 b = *(float4*)&Wl[k * 32 + c0];
    acc[0][0] += a0 * b.x; acc[0][1] += a0 * b.y; acc[0][2] += a0 * b.z; acc[0][3] += a0 * b.w;
    acc[1][0] += a1 * b.x; acc[1][1] += a1 * b.y; acc[1][2] += a1 * b.z; acc[1][3] += a1 * b.w;
  }

  float as[4], ad[4];
  #pragma unroll
  for (int j = 0; j < 4; j++){ as[j] = a_src[c0 + j]; ad[j] = a_dst[c0 + j]; }
  #pragma unroll
  for (int i = 0; i < 2; i++){
    int row = rb + r0 + i;
    if (row < N)
      *(float4*)&h2[(size_t)row * 32 + c0] = make_float4(acc[i][0], acc[i][1], acc[i][2], acc[i][3]);
    float ps = 0.f, pd = 0.f;
    #pragma unroll
    for (int j = 0; j < 4; j++){ ps += acc[i][j] * as[j]; pd += acc[i][j] * ad[j]; }
    ps += __shfl_xor(ps, 1, 8); ps += __shfl_xor(ps, 2, 8); ps += __shfl_xor(ps, 4, 8);
    pd += __shfl_xor(pd, 1, 8); pd += __shfl_xor(pd, 2, 8); pd += __shfl_xor(pd, 4, 8);
    if ((t & 7) == 0 && row < N){ s_src2[row] = ps; s_dst2[row] = pd; }
  }
}

// ---------------- agg2: 8 nodes/block (32 ch each), x4 unrolled, writes final out ----------------
__global__ __launch_bounds__(256) void k_agg2(
    const int* __restrict__ row_ptr, const int* __restrict__ csr_src,
    const float* __restrict__ wE, const float* __restrict__ h2,
    const float* __restrict__ b2, float* __restrict__ out, int N){
  int n = blockIdx.x * 8 + (threadIdx.x >> 5);
  if (n >= N) return;
  int c = threadIdx.x & 31;
  int beg = row_ptr[n], end = row_ptr[n + 1];
  float acc = 0.f, sw = 0.f;
  int e = beg;
  for (; e + 4 <= end; e += 4){
    int s0 = csr_src[e], s1 = csr_src[e+1], s2 = csr_src[e+2], s3 = csr_src[e+3];
    float w0 = wE[e], w1 = wE[e+1], w2 = wE[e+2], w3 = wE[e+3];
    acc += w0 * h2[(size_t)s0 * 32 + c] + w1 * h2[(size_t)s1 * 32 + c]
         + w2 * h2[(size_t)s2 * 32 + c] + w3 * h2[(size_t)s3 * 32 + c];
    sw += w0 + w1 + w2 + w3;
  }
  for (; e < end; e++){
    int s = csr_src[e];
    float w = wE[e];
    acc += w * h2[(size_t)s * 32 + c];
    sw += w;
  }
  out[(size_t)n * 32 + c] = acc / (sw + 1e-16f) + b2[c];
}

extern "C" void kernel_launch(void* const* d_in, const int* in_sizes, int n_in,
                              void* d_out, int out_size, void* d_ws, size_t ws_size,
                              hipStream_t stream) {
  const float* x      = (const float*)d_in[0];
  const int*   ei     = (const int*)  d_in[1];
  const float* W1     = (const float*)d_in[2];
  const float* a_src1 = (const float*)d_in[3];
  const float* a_dst1 = (const float*)d_in[4];
  const float* b1     = (const float*)d_in[5];
  const float* W2     = (const float*)d_in[6];
  const float* a_src2 = (const float*)d_in[7];
  const float* a_dst2 = (const float*)d_in[8];
  const float* b2     = (const float*)d_in[9];
  float* out = (float*)d_out;

  int N = in_sizes[0] / 128;
  int E = in_sizes[1] / 2;
  const int* srcp = ei;
  const int* dstp = ei + E;
  int total = E + N;

  char* p = (char*)d_ws;
  auto alloc = [&](size_t bytes) -> void* {
    void* r = (void*)p; p += (bytes + 255) & ~(size_t)255; return r;
  };
  unsigned short* h_bf = (unsigned short*)alloc((size_t)N * 128 * 2);
  float* out1 = (float*)alloc((size_t)N * 128 * 4);
  float* h2   = (float*)alloc((size_t)N * 32 * 4);
  float* ss1  = (float*)alloc((size_t)N * 4 * 4);
  float* sd1  = (float*)alloc((size_t)N * 4 * 4);
  float* ss2  = (float*)alloc((size_t)N * 4);
  float* sd2  = (float*)alloc((size_t)N * 4);
  float* we1  = (float*)alloc((size_t)total * 4 * 4);
  float* we2  = (float*)alloc((size_t)total * 4);
  int* deg    = (int*)alloc((size_t)N * 4);
  int* rowp   = (int*)alloc((size_t)(N + 1) * 4);
  int* cursor = (int*)alloc((size_t)N * 4);
  int* csr    = (int*)alloc((size_t)total * 4);
  int* csrd   = (int*)alloc((size_t)total * 4);
  int* parts  = (int*)alloc(256 * 4);
  (void)ws_size; (void)n_in; (void)out_size;

  hipMemsetAsync(deg, 0, (size_t)N * 4, stream);
  k_count<<<(E + 255) / 256, 256, 0, stream>>>(dstp, E, deg);
  int NB = (N + 1023) / 1024;
  k_scan1<<<NB, 256, 0, stream>>>(deg, rowp, parts, N);
  k_scan2<<<1, 128, 0, stream>>>(parts, NB);
  k_scan3<<<(N + 255) / 256, 256, 0, stream>>>(rowp, cursor, parts, N, total);
  k_scatter<<<(total + 255) / 256, 256, 0, stream>>>(srcp, dstp, E, N, cursor, csr, csrd);

  k_gemm1<<<dim3((N + 63) / 64, 2), 256, 0, stream>>>(x, W1, a_src1, a_dst1, h_bf, ss1, sd1, N);
  k_w1<<<(total + 255) / 256, 256, 0, stream>>>(csr, csrd, ss1, sd1, we1, total);
  k_agg1<<<(N + 3) / 4, 256, 0, stream>>>(rowp, csr, we1, (const __hip_bfloat162*)h_bf, out1, N);
  k_gemm2<<<(N + 63) / 64, 256, 0, stream>>>(out1, b1, W2, a_src2, a_dst2, h2, ss2, sd2, N);
  k_w2<<<(total + 255) / 256, 256, 0, stream>>>(csr, csrd, ss2, sd2, we2, total);
  k_agg2<<<(N + 7) / 8, 256, 0, stream>>>(rowp, csr, we2, h2, b2, out, N);
}

// Round 3
// 507.727 us; speedup vs baseline: 3.7626x; 3.7626x over previous
//
#include <hip/hip_runtime.h>
#include <hip/hip_bf16.h>

#define NEG 0.2f

__device__ __forceinline__ float lrelu(float x){ return x > 0.f ? x : NEG * x; }
__device__ __forceinline__ float elu_f(float x){ return x > 0.f ? x : expm1f(x); }
__device__ __forceinline__ unsigned short f2bf(float f){
  unsigned int u = __float_as_uint(f);
  unsigned int r = u + 0x7fffu + ((u >> 16) & 1u);   // round-to-nearest-even
  return (unsigned short)(r >> 16);
}

// ---------------- CSR build ----------------
__global__ void k_count(const int* __restrict__ dst, int E, int* deg){
  int e = blockIdx.x * blockDim.x + threadIdx.x;
  if (e < E) atomicAdd(&deg[dst[e]], 1);
}

__global__ void k_scan1(const int* __restrict__ deg, int* row_ptr, int* partials, int N){
  __shared__ int sd[256];
  int t = threadIdx.x;
  int base = blockIdx.x * 1024 + t * 4;
  int v[4]; int s = 0;
  #pragma unroll
  for (int j = 0; j < 4; j++){ int i = base + j; v[j] = (i < N) ? (deg[i] + 1) : 0; s += v[j]; }
  sd[t] = s; __syncthreads();
  for (int off = 1; off < 256; off <<= 1){
    int x = (t >= off) ? sd[t - off] : 0;
    __syncthreads(); sd[t] += x; __syncthreads();
  }
  int pre = (t > 0) ? sd[t - 1] : 0;
  #pragma unroll
  for (int j = 0; j < 4; j++){ int i = base + j; if (i < N) row_ptr[i] = pre; pre += v[j]; }
  if (t == 255) partials[blockIdx.x] = sd[255];
}

__global__ void k_scan2(int* partials, int NB){
  __shared__ int sd[128];
  int t = threadIdx.x;
  int v = (t < NB) ? partials[t] : 0;
  sd[t] = v; __syncthreads();
  for (int off = 1; off < 128; off <<= 1){
    int x = (t >= off) ? sd[t - off] : 0;
    __syncthreads(); sd[t] += x; __syncthreads();
  }
  if (t < NB) partials[t] = sd[t] - v;   // exclusive
}

__global__ void k_scan3(int* row_ptr, int* cursor, const int* __restrict__ partials, int N, int total){
  int i = blockIdx.x * blockDim.x + threadIdx.x;
  if (i < N){ int r = row_ptr[i] + partials[i >> 10]; row_ptr[i] = r; cursor[i] = r; }
  if (i == 0) row_ptr[N] = total;
}

__global__ void k_scatter(const int* __restrict__ src, const int* __restrict__ dst,
                          int E, int N, int* cursor,
                          int* __restrict__ csr_src, int* __restrict__ csr_dst){
  int e = blockIdx.x * blockDim.x + threadIdx.x;
  int tot = E + N;
  if (e >= tot) return;
  int s, d;
  if (e < E){ s = src[e]; d = dst[e]; } else { s = e - E; d = s; }
  int pos = atomicAdd(&cursor[d], 1);
  csr_src[pos] = s;
  csr_dst[pos] = d;
}

// ---------------- per-edge attention weights ----------------
__global__ void k_w1(const int* __restrict__ csr_src, const int* __restrict__ csr_dst,
                     const float* __restrict__ ss, const float* __restrict__ sd,
                     float* __restrict__ we, int total){
  int e = blockIdx.x * blockDim.x + threadIdx.x;
  if (e >= total) return;
  int s = csr_src[e], d = csr_dst[e];
  float4 a = *(const float4*)&ss[(size_t)s * 4];
  float4 b = *(const float4*)&sd[(size_t)d * 4];
  float4 w;
  w.x = __expf(lrelu(a.x + b.x));
  w.y = __expf(lrelu(a.y + b.y));
  w.z = __expf(lrelu(a.z + b.z));
  w.w = __expf(lrelu(a.w + b.w));
  *(float4*)&we[(size_t)e * 4] = w;
}

__global__ void k_w2(const int* __restrict__ csr_src, const int* __restrict__ csr_dst,
                     const float* __restrict__ ss, const float* __restrict__ sd,
                     float* __restrict__ we, int total){
  int e = blockIdx.x * blockDim.x + threadIdx.x;
  if (e >= total) return;
  int s = csr_src[e], d = csr_dst[e];
  we[e] = __expf(lrelu(ss[s] + sd[d]));
}

// ---------------- GEMM1: x[N,128] @ W[128,128] -> h_bf[N,128] (bf16), + s_src1/s_dst1[N,4]
// 64 rows x 128 cols per block, K-chunked by 32, X transposed in LDS. 4x8 microtile.
// NO float4 arrays in the hot loop (R2's float4 a[4] + ternary spilled to scratch: 4.5 GB traffic).
__global__ __launch_bounds__(256, 4) void k_gemm1(
    const float* __restrict__ x, const float* __restrict__ W,
    const float* __restrict__ a_src, const float* __restrict__ a_dst,
    unsigned short* __restrict__ h_bf, float* __restrict__ s_src, float* __restrict__ s_dst, int N){
  __shared__ __align__(16) float Xt[32 * 68];    // [kk][row], stride 68 (mult of 4 -> aligned b128)
  __shared__ __align__(16) float Wl[32 * 128];   // [kk][col]
  int t = threadIdx.x;
  int rb = blockIdx.x * 64;

  int cg = t & 15, rg = t >> 4;
  int c0 = cg * 8, r0 = rg * 4;

  float acc[4][8] = {};

  for (int ko = 0; ko < 128; ko += 32){
    // stage W chunk: 32 k x 128 cols = 1024 float4, 4 per thread, coalesced
    #pragma unroll
    for (int j = 0; j < 4; j++){
      int fi = j * 256 + t;
      int kr = fi >> 5, c4 = fi & 31;
      float4 w = *(const float4*)&W[(size_t)(ko + kr) * 128 + c4 * 4];
      *(float4*)&Wl[kr * 128 + c4 * 4] = w;
    }
    // stage X chunk transposed: 64 rows x 32 k = 512 float4, 2 per thread
    #pragma unroll
    for (int j = 0; j < 2; j++){
      int fi = j * 256 + t;
      int row = fi >> 3, c4 = fi & 7;
      int gr = rb + row;
      float4 v = make_float4(0.f, 0.f, 0.f, 0.f);
      if (gr < N) v = *(const float4*)&x[(size_t)gr * 128 + ko + c4 * 4];
      int kb = c4 * 4;
      Xt[(kb + 0) * 68 + row] = v.x;
      Xt[(kb + 1) * 68 + row] = v.y;
      Xt[(kb + 2) * 68 + row] = v.z;
      Xt[(kb + 3) * 68 + row] = v.w;
    }
    __syncthreads();

    #pragma unroll 8
    for (int kk = 0; kk < 32; kk++){
      float4 a  = *(float4*)&Xt[kk * 68 + r0];
      float4 b0 = *(float4*)&Wl[kk * 128 + c0];
      float4 b1 = *(float4*)&Wl[kk * 128 + c0 + 4];
      float ar0 = a.x, ar1 = a.y, ar2 = a.z, ar3 = a.w;
      acc[0][0] += ar0 * b0.x; acc[0][1] += ar0 * b0.y; acc[0][2] += ar0 * b0.z; acc[0][3] += ar0 * b0.w;
      acc[0][4] += ar0 * b1.x; acc[0][5] += ar0 * b1.y; acc[0][6] += ar0 * b1.z; acc[0][7] += ar0 * b1.w;
      acc[1][0] += ar1 * b0.x; acc[1][1] += ar1 * b0.y; acc[1][2] += ar1 * b0.z; acc[1][3] += ar1 * b0.w;
      acc[1][4] += ar1 * b1.x; acc[1][5] += ar1 * b1.y; acc[1][6] += ar1 * b1.z; acc[1][7] += ar1 * b1.w;
      acc[2][0] += ar2 * b0.x; acc[2][1] += ar2 * b0.y; acc[2][2] += ar2 * b0.z; acc[2][3] += ar2 * b0.w;
      acc[2][4] += ar2 * b1.x; acc[2][5] += ar2 * b1.y; acc[2][6] += ar2 * b1.z; acc[2][7] += ar2 * b1.w;
      acc[3][0] += ar3 * b0.x; acc[3][1] += ar3 * b0.y; acc[3][2] += ar3 * b0.z; acc[3][3] += ar3 * b0.w;
      acc[3][4] += ar3 * b1.x; acc[3][5] += ar3 * b1.y; acc[3][6] += ar3 * b1.z; acc[3][7] += ar3 * b1.w;
    }
    __syncthreads();
  }

  int head = cg >> 2;              // c0 >> 5
  float as[8], ad[8];
  #pragma unroll
  for (int j = 0; j < 8; j++){ as[j] = a_src[c0 + j]; ad[j] = a_dst[c0 + j]; }
  #pragma unroll
  for (int i = 0; i < 4; i++){
    int row = rb + r0 + i;
    bool ok = row < N;
    if (ok){
      ushort4 o0, o1;
      o0.x = f2bf(acc[i][0]); o0.y = f2bf(acc[i][1]); o0.z = f2bf(acc[i][2]); o0.w = f2bf(acc[i][3]);
      o1.x = f2bf(acc[i][4]); o1.y = f2bf(acc[i][5]); o1.z = f2bf(acc[i][6]); o1.w = f2bf(acc[i][7]);
      *(ushort4*)&h_bf[(size_t)row * 128 + c0]     = o0;
      *(ushort4*)&h_bf[(size_t)row * 128 + c0 + 4] = o1;
    }
    float ps = 0.f, pd = 0.f;
    #pragma unroll
    for (int j = 0; j < 8; j++){ ps += acc[i][j] * as[j]; pd += acc[i][j] * ad[j]; }
    ps += __shfl_xor(ps, 1, 4); ps += __shfl_xor(ps, 2, 4);
    pd += __shfl_xor(pd, 1, 4); pd += __shfl_xor(pd, 2, 4);
    if ((t & 3) == 0 && ok){ s_src[(size_t)row * 4 + head] = ps; s_dst[(size_t)row * 4 + head] = pd; }
  }
}

// ---------------- agg1: 1 wave per node, bf16x2 gather, x4 unrolled ----------------
__global__ __launch_bounds__(256) void k_agg1(
    const int* __restrict__ row_ptr, const int* __restrict__ csr_src,
    const float* __restrict__ we, const __hip_bfloat162* __restrict__ hb2,
    float* __restrict__ out1, int N){
  int n = blockIdx.x * 4 + (threadIdx.x >> 6);
  if (n >= N) return;
  int l = threadIdx.x & 63;
  int hd = l >> 4;                 // head = channel/32, channels 2l,2l+1
  int beg = row_ptr[n], end = row_ptr[n + 1];
  float ax = 0.f, ay = 0.f, sw = 0.f;
  int e = beg;
  for (; e + 4 <= end; e += 4){
    int s0 = csr_src[e], s1 = csr_src[e+1], s2 = csr_src[e+2], s3 = csr_src[e+3];
    float w0 = we[(size_t)e*4 + hd],     w1 = we[(size_t)e*4 + 4 + hd];
    float w2 = we[(size_t)e*4 + 8 + hd], w3 = we[(size_t)e*4 + 12 + hd];
    float2 v0 = __bfloat1622float2(hb2[(size_t)s0 * 64 + l]);
    float2 v1 = __bfloat1622float2(hb2[(size_t)s1 * 64 + l]);
    float2 v2 = __bfloat1622float2(hb2[(size_t)s2 * 64 + l]);
    float2 v3 = __bfloat1622float2(hb2[(size_t)s3 * 64 + l]);
    ax += w0*v0.x + w1*v1.x + w2*v2.x + w3*v3.x;
    ay += w0*v0.y + w1*v1.y + w2*v2.y + w3*v3.y;
    sw += w0 + w1 + w2 + w3;
  }
  for (; e < end; e++){
    int s = csr_src[e];
    float w = we[(size_t)e*4 + hd];
    float2 v = __bfloat1622float2(hb2[(size_t)s * 64 + l]);
    ax += w*v.x; ay += w*v.y; sw += w;
  }
  float inv = 1.f / (sw + 1e-16f);
  *(float2*)&out1[(size_t)n * 128 + l * 2] = make_float2(ax * inv, ay * inv);
}

// ---------------- GEMM2: elu(out1+b1)[N,128] @ W2[128,32] -> h2[N,32], + s_src2/s_dst2[N] ----------------
__global__ __launch_bounds__(256) void k_gemm2(
    const float* __restrict__ out1, const float* __restrict__ b1,
    const float* __restrict__ W2,
    const float* __restrict__ a_src, const float* __restrict__ a_dst,
    float* __restrict__ h2, float* __restrict__ s_src2, float* __restrict__ s_dst2, int N){
  __shared__ __align__(16) float Wl[128 * 32];
  __shared__ __align__(16) float Xl[64 * 132];
  int t = threadIdx.x;
  int rb = blockIdx.x * 64;

  const float4* Wg4 = (const float4*)W2;
  float4* Wl4 = (float4*)Wl;
  #pragma unroll
  for (int j = 0; j < 4; j++) Wl4[j * 256 + t] = Wg4[j * 256 + t];

  #pragma unroll
  for (int j = 0; j < 8; j++){
    int fi = j * 256 + t;
    int row = fi >> 5; int kc = (fi & 31) * 4;
    float4 v = make_float4(0.f, 0.f, 0.f, 0.f);
    if (rb + row < N){
      float4 xv = *(const float4*)&out1[(size_t)(rb + row) * 128 + kc];
      float4 bv = *(const float4*)&b1[kc];
      v.x = elu_f(xv.x + bv.x); v.y = elu_f(xv.y + bv.y);
      v.z = elu_f(xv.z + bv.z); v.w = elu_f(xv.w + bv.w);
    }
    *(float4*)&Xl[row * 132 + kc] = v;
  }
  __syncthreads();

  int cg = t & 7, rg = t >> 3;
  int c0 = cg * 4, r0 = rg * 2;
  float acc[2][4] = {};

  #pragma unroll 8
  for (int k = 0; k < 128; k++){
    float a0 = Xl[r0 * 132 + k];
    float a1 = Xl[(r0 + 1) * 132 + k];
    float4 b = *(float4*)&Wl[k * 32 + c0];
    acc[0][0] += a0 * b.x; acc[0][1] += a0 * b.y; acc[0][2] += a0 * b.z; acc[0][3] += a0 * b.w;
    acc[1][0] += a1 * b.x; acc[1][1] += a1 * b.y; acc[1][2] += a1 * b.z; acc[1][3] += a1 * b.w;
  }

  float as[4], ad[4];
  #pragma unroll
  for (int j = 0; j < 4; j++){ as[j] = a_src[c0 + j]; ad[j] = a_dst[c0 + j]; }
  #pragma unroll
  for (int i = 0; i < 2; i++){
    int row = rb + r0 + i;
    if (row < N)
      *(float4*)&h2[(size_t)row * 32 + c0] = make_float4(acc[i][0], acc[i][1], acc[i][2], acc[i][3]);
    float ps = 0.f, pd = 0.f;
    #pragma unroll
    for (int j = 0; j < 4; j++){ ps += acc[i][j] * as[j]; pd += acc[i][j] * ad[j]; }
    ps += __shfl_xor(ps, 1, 8); ps += __shfl_xor(ps, 2, 8); ps += __shfl_xor(ps, 4, 8);
    pd += __shfl_xor(pd, 1, 8); pd += __shfl_xor(pd, 2, 8); pd += __shfl_xor(pd, 4, 8);
    if ((t & 7) == 0 && row < N){ s_src2[row] = ps; s_dst2[row] = pd; }
  }
}

// ---------------- agg2: 8 nodes/block (32 ch each), x4 unrolled, writes final out ----------------
__global__ __launch_bounds__(256) void k_agg2(
    const int* __restrict__ row_ptr, const int* __restrict__ csr_src,
    const float* __restrict__ wE, const float* __restrict__ h2,
    const float* __restrict__ b2, float* __restrict__ out, int N){
  int n = blockIdx.x * 8 + (threadIdx.x >> 5);
  if (n >= N) return;
  int c = threadIdx.x & 31;
  int beg = row_ptr[n], end = row_ptr[n + 1];
  float acc = 0.f, sw = 0.f;
  int e = beg;
  for (; e + 4 <= end; e += 4){
    int s0 = csr_src[e], s1 = csr_src[e+1], s2 = csr_src[e+2], s3 = csr_src[e+3];
    float w0 = wE[e], w1 = wE[e+1], w2 = wE[e+2], w3 = wE[e+3];
    acc += w0 * h2[(size_t)s0 * 32 + c] + w1 * h2[(size_t)s1 * 32 + c]
         + w2 * h2[(size_t)s2 * 32 + c] + w3 * h2[(size_t)s3 * 32 + c];
    sw += w0 + w1 + w2 + w3;
  }
  for (; e < end; e++){
    int s = csr_src[e];
    float w = wE[e];
    acc += w * h2[(size_t)s * 32 + c];
    sw += w;
  }
  out[(size_t)n * 32 + c] = acc / (sw + 1e-16f) + b2[c];
}

extern "C" void kernel_launch(void* const* d_in, const int* in_sizes, int n_in,
                              void* d_out, int out_size, void* d_ws, size_t ws_size,
                              hipStream_t stream) {
  const float* x      = (const float*)d_in[0];
  const int*   ei     = (const int*)  d_in[1];
  const float* W1     = (const float*)d_in[2];
  const float* a_src1 = (const float*)d_in[3];
  const float* a_dst1 = (const float*)d_in[4];
  const float* b1     = (const float*)d_in[5];
  const float* W2     = (const float*)d_in[6];
  const float* a_src2 = (const float*)d_in[7];
  const float* a_dst2 = (const float*)d_in[8];
  const float* b2     = (const float*)d_in[9];
  float* out = (float*)d_out;

  int N = in_sizes[0] / 128;
  int E = in_sizes[1] / 2;
  const int* srcp = ei;
  const int* dstp = ei + E;
  int total = E + N;

  char* p = (char*)d_ws;
  auto alloc = [&](size_t bytes) -> void* {
    void* r = (void*)p; p += (bytes + 255) & ~(size_t)255; return r;
  };
  unsigned short* h_bf = (unsigned short*)alloc((size_t)N * 128 * 2);
  float* out1 = (float*)alloc((size_t)N * 128 * 4);
  float* h2   = (float*)alloc((size_t)N * 32 * 4);
  float* ss1  = (float*)alloc((size_t)N * 4 * 4);
  float* sd1  = (float*)alloc((size_t)N * 4 * 4);
  float* ss2  = (float*)alloc((size_t)N * 4);
  float* sd2  = (float*)alloc((size_t)N * 4);
  float* we1  = (float*)alloc((size_t)total * 4 * 4);
  float* we2  = (float*)alloc((size_t)total * 4);
  int* deg    = (int*)alloc((size_t)N * 4);
  int* rowp   = (int*)alloc((size_t)(N + 1) * 4);
  int* cursor = (int*)alloc((size_t)N * 4);
  int* csr    = (int*)alloc((size_t)total * 4);
  int* csrd   = (int*)alloc((size_t)total * 4);
  int* parts  = (int*)alloc(256 * 4);
  (void)ws_size; (void)n_in; (void)out_size;

  hipMemsetAsync(deg, 0, (size_t)N * 4, stream);
  k_count<<<(E + 255) / 256, 256, 0, stream>>>(dstp, E, deg);
  int NB = (N + 1023) / 1024;
  k_scan1<<<NB, 256, 0, stream>>>(deg, rowp, parts, N);
  k_scan2<<<1, 128, 0, stream>>>(parts, NB);
  k_scan3<<<(N + 255) / 256, 256, 0, stream>>>(rowp, cursor, parts, N, total);
  k_scatter<<<(total + 255) / 256, 256, 0, stream>>>(srcp, dstp, E, N, cursor, csr, csrd);

  k_gemm1<<<(N + 63) / 64, 256, 0, stream>>>(x, W1, a_src1, a_dst1, h_bf, ss1, sd1, N);
  k_w1<<<(total + 255) / 256, 256, 0, stream>>>(csr, csrd, ss1, sd1, we1, total);
  k_agg1<<<(N + 3) / 4, 256, 0, stream>>>(rowp, csr, we1, (const __hip_bfloat162*)h_bf, out1, N);
  k_gemm2<<<(N + 63) / 64, 256, 0, stream>>>(out1, b1, W2, a_src2, a_dst2, h2, ss2, sd2, N);
  k_w2<<<(total + 255) / 256, 256, 0, stream>>>(csr, csrd, ss2, sd2, we2, total);
  k_agg2<<<(N + 7) / 8, 256, 0, stream>>>(rowp, csr, we2, h2, b2, out, N);
}

// Round 5
// 403.108 us; speedup vs baseline: 4.7391x; 1.2595x over previous
//
#include <hip/hip_runtime.h>
#include <hip/hip_bf16.h>

#define NEG 0.2f

__device__ __forceinline__ float lrelu(float x){ return x > 0.f ? x : NEG * x; }
__device__ __forceinline__ float elu_f(float x){ return x > 0.f ? x : expm1f(x); }
__device__ __forceinline__ unsigned short f2bf(float f){
  unsigned int u = __float_as_uint(f);
  unsigned int r = u + 0x7fffu + ((u >> 16) & 1u);   // round-to-nearest-even
  return (unsigned short)(r >> 16);
}
__device__ __forceinline__ float bf2f(unsigned short u){
  return __uint_as_float(((unsigned int)u) << 16);
}

// ---------------- CSR build ----------------
// count + per-edge rank (so scatter needs no atomic)
__global__ void k_count(const int* __restrict__ dst, int E, int* deg, int* __restrict__ rank){
  int e = blockIdx.x * blockDim.x + threadIdx.x;
  if (e < E) rank[e] = atomicAdd(&deg[dst[e]], 1);
}

__global__ void k_scan1(const int* __restrict__ deg, int* row_ptr, int* partials, int N){
  __shared__ int sd[256];
  int t = threadIdx.x;
  int base = blockIdx.x * 1024 + t * 4;
  int v[4]; int s = 0;
  #pragma unroll
  for (int j = 0; j < 4; j++){ int i = base + j; v[j] = (i < N) ? (deg[i] + 1) : 0; s += v[j]; }
  sd[t] = s; __syncthreads();
  for (int off = 1; off < 256; off <<= 1){
    int x = (t >= off) ? sd[t - off] : 0;
    __syncthreads(); sd[t] += x; __syncthreads();
  }
  int pre = (t > 0) ? sd[t - 1] : 0;
  #pragma unroll
  for (int j = 0; j < 4; j++){ int i = base + j; if (i < N) row_ptr[i] = pre; pre += v[j]; }
  if (t == 255) partials[blockIdx.x] = sd[255];
}

__global__ void k_scan2(int* partials, int NB){
  __shared__ int sd[128];
  int t = threadIdx.x;
  int v = (t < NB) ? partials[t] : 0;
  sd[t] = v; __syncthreads();
  for (int off = 1; off < 128; off <<= 1){
    int x = (t >= off) ? sd[t - off] : 0;
    __syncthreads(); sd[t] += x; __syncthreads();
  }
  if (t < NB) partials[t] = sd[t] - v;   // exclusive
}

__global__ void k_scan3(int* row_ptr, const int* __restrict__ partials, int N, int total){
  int i = blockIdx.x * blockDim.x + threadIdx.x;
  if (i < N){ int r = row_ptr[i] + partials[i >> 10]; row_ptr[i] = r; }
  if (i == 0) row_ptr[N] = total;
}

// atomic-free scatter: pos = rowp[d] + rank[e]; self-loop of node d goes at rowp[d]+deg[d]
__global__ void k_scatter(const int* __restrict__ src, const int* __restrict__ dst,
                          const int* __restrict__ rank, const int* __restrict__ deg,
                          const int* __restrict__ rowp,
                          int E, int N, int* __restrict__ csr_src){
  int e = blockIdx.x * blockDim.x + threadIdx.x;
  int tot = E + N;
  if (e >= tot) return;
  int pos, s;
  if (e < E){ int d = dst[e]; s = src[e]; pos = rowp[d] + rank[e]; }
  else      { int d = e - E;  s = d;      pos = rowp[d] + deg[d]; }
  csr_src[pos] = s;
}

// ---------------- GEMM1: x[N,128] @ W[128,128] -> h_bf[N,128] (bf16), + s_src1/s_dst1[N,4]
// 64 rows x 128 cols per block, K-chunked by 32, X transposed in LDS. 4x8 microtile.
// NO float4 arrays in the hot loop (R2's float4 a[4] + ternary spilled to scratch: 4.5 GB traffic).
__global__ __launch_bounds__(256, 4) void k_gemm1(
    const float* __restrict__ x, const float* __restrict__ W,
    const float* __restrict__ a_src, const float* __restrict__ a_dst,
    unsigned short* __restrict__ h_bf, float* __restrict__ s_src, float* __restrict__ s_dst, int N){
  __shared__ __align__(16) float Xt[32 * 68];    // [kk][row], stride 68
  __shared__ __align__(16) float Wl[32 * 128];   // [kk][col]
  int t = threadIdx.x;
  int rb = blockIdx.x * 64;

  int cg = t & 15, rg = t >> 4;
  int c0 = cg * 8, r0 = rg * 4;

  float acc[4][8] = {};

  for (int ko = 0; ko < 128; ko += 32){
    #pragma unroll
    for (int j = 0; j < 4; j++){
      int fi = j * 256 + t;
      int kr = fi >> 5, c4 = fi & 31;
      float4 w = *(const float4*)&W[(size_t)(ko + kr) * 128 + c4 * 4];
      *(float4*)&Wl[kr * 128 + c4 * 4] = w;
    }
    #pragma unroll
    for (int j = 0; j < 2; j++){
      int fi = j * 256 + t;
      int row = fi >> 3, c4 = fi & 7;
      int gr = rb + row;
      float4 v = make_float4(0.f, 0.f, 0.f, 0.f);
      if (gr < N) v = *(const float4*)&x[(size_t)gr * 128 + ko + c4 * 4];
      int kb = c4 * 4;
      Xt[(kb + 0) * 68 + row] = v.x;
      Xt[(kb + 1) * 68 + row] = v.y;
      Xt[(kb + 2) * 68 + row] = v.z;
      Xt[(kb + 3) * 68 + row] = v.w;
    }
    __syncthreads();

    #pragma unroll 8
    for (int kk = 0; kk < 32; kk++){
      float4 a  = *(float4*)&Xt[kk * 68 + r0];
      float4 b0 = *(float4*)&Wl[kk * 128 + c0];
      float4 b1 = *(float4*)&Wl[kk * 128 + c0 + 4];
      float ar0 = a.x, ar1 = a.y, ar2 = a.z, ar3 = a.w;
      acc[0][0] += ar0 * b0.x; acc[0][1] += ar0 * b0.y; acc[0][2] += ar0 * b0.z; acc[0][3] += ar0 * b0.w;
      acc[0][4] += ar0 * b1.x; acc[0][5] += ar0 * b1.y; acc[0][6] += ar0 * b1.z; acc[0][7] += ar0 * b1.w;
      acc[1][0] += ar1 * b0.x; acc[1][1] += ar1 * b0.y; acc[1][2] += ar1 * b0.z; acc[1][3] += ar1 * b0.w;
      acc[1][4] += ar1 * b1.x; acc[1][5] += ar1 * b1.y; acc[1][6] += ar1 * b1.z; acc[1][7] += ar1 * b1.w;
      acc[2][0] += ar2 * b0.x; acc[2][1] += ar2 * b0.y; acc[2][2] += ar2 * b0.z; acc[2][3] += ar2 * b0.w;
      acc[2][4] += ar2 * b1.x; acc[2][5] += ar2 * b1.y; acc[2][6] += ar2 * b1.z; acc[2][7] += ar2 * b1.w;
      acc[3][0] += ar3 * b0.x; acc[3][1] += ar3 * b0.y; acc[3][2] += ar3 * b0.z; acc[3][3] += ar3 * b0.w;
      acc[3][4] += ar3 * b1.x; acc[3][5] += ar3 * b1.y; acc[3][6] += ar3 * b1.z; acc[3][7] += ar3 * b1.w;
    }
    __syncthreads();
  }

  int head = cg >> 2;
  float as[8], ad[8];
  #pragma unroll
  for (int j = 0; j < 8; j++){ as[j] = a_src[c0 + j]; ad[j] = a_dst[c0 + j]; }
  #pragma unroll
  for (int i = 0; i < 4; i++){
    int row = rb + r0 + i;
    bool ok = row < N;
    if (ok){
      ushort4 o0, o1;
      o0.x = f2bf(acc[i][0]); o0.y = f2bf(acc[i][1]); o0.z = f2bf(acc[i][2]); o0.w = f2bf(acc[i][3]);
      o1.x = f2bf(acc[i][4]); o1.y = f2bf(acc[i][5]); o1.z = f2bf(acc[i][6]); o1.w = f2bf(acc[i][7]);
      *(ushort4*)&h_bf[(size_t)row * 128 + c0]     = o0;
      *(ushort4*)&h_bf[(size_t)row * 128 + c0 + 4] = o1;
    }
    float ps = 0.f, pd = 0.f;
    #pragma unroll
    for (int j = 0; j < 8; j++){ ps += acc[i][j] * as[j]; pd += acc[i][j] * ad[j]; }
    ps += __shfl_xor(ps, 1, 4); ps += __shfl_xor(ps, 2, 4);
    pd += __shfl_xor(pd, 1, 4); pd += __shfl_xor(pd, 2, 4);
    if ((t & 3) == 0 && ok){ s_src[(size_t)row * 4 + head] = ps; s_dst[(size_t)row * 4 + head] = pd; }
  }
}

// ---------------- agg1: 1 wave per node, fused edge weights, bf16 in/out ----------------
__global__ __launch_bounds__(256) void k_agg1(
    const int* __restrict__ row_ptr, const int* __restrict__ csr_src,
    const float* __restrict__ ss, const float* __restrict__ sdst,
    const __hip_bfloat162* __restrict__ hb2,
    unsigned int* __restrict__ out1_bf, int N){
  int n = blockIdx.x * 4 + (threadIdx.x >> 6);
  if (n >= N) return;
  int l = threadIdx.x & 63;
  int hd = l >> 4;                 // head = channel/32, channels 2l,2l+1
  float sdv = sdst[(size_t)n * 4 + hd];
  int beg = row_ptr[n], end = row_ptr[n + 1];
  float ax = 0.f, ay = 0.f, sw = 0.f;
  int e = beg;
  for (; e + 4 <= end; e += 4){
    int s0 = csr_src[e], s1 = csr_src[e+1], s2 = csr_src[e+2], s3 = csr_src[e+3];
    float w0 = __expf(lrelu(ss[(size_t)s0*4 + hd] + sdv));
    float w1 = __expf(lrelu(ss[(size_t)s1*4 + hd] + sdv));
    float w2 = __expf(lrelu(ss[(size_t)s2*4 + hd] + sdv));
    float w3 = __expf(lrelu(ss[(size_t)s3*4 + hd] + sdv));
    float2 v0 = __bfloat1622float2(hb2[(size_t)s0 * 64 + l]);
    float2 v1 = __bfloat1622float2(hb2[(size_t)s1 * 64 + l]);
    float2 v2 = __bfloat1622float2(hb2[(size_t)s2 * 64 + l]);
    float2 v3 = __bfloat1622float2(hb2[(size_t)s3 * 64 + l]);
    ax += w0*v0.x + w1*v1.x + w2*v2.x + w3*v3.x;
    ay += w0*v0.y + w1*v1.y + w2*v2.y + w3*v3.y;
    sw += w0 + w1 + w2 + w3;
  }
  for (; e < end; e++){
    int s = csr_src[e];
    float w = __expf(lrelu(ss[(size_t)s*4 + hd] + sdv));
    float2 v = __bfloat1622float2(hb2[(size_t)s * 64 + l]);
    ax += w*v.x; ay += w*v.y; sw += w;
  }
  float inv = 1.f / (sw + 1e-16f);
  unsigned int lo = f2bf(ax * inv), hi = f2bf(ay * inv);
  out1_bf[(size_t)n * 64 + l] = (hi << 16) | lo;
}

// ---------------- GEMM2: elu(out1_bf+b1)[N,128] @ W2[128,32] -> h2_bf[N,32], + s_src2/s_dst2[N]
__global__ __launch_bounds__(256) void k_gemm2(
    const unsigned int* __restrict__ out1_bf, const float* __restrict__ b1,
    const float* __restrict__ W2,
    const float* __restrict__ a_src, const float* __restrict__ a_dst,
    unsigned short* __restrict__ h2_bf, float* __restrict__ s_src2, float* __restrict__ s_dst2, int N){
  __shared__ __align__(16) float Wl[128 * 32];
  __shared__ __align__(16) float Xl[64 * 132];
  int t = threadIdx.x;
  int rb = blockIdx.x * 64;

  const float4* Wg4 = (const float4*)W2;
  float4* Wl4 = (float4*)Wl;
  #pragma unroll
  for (int j = 0; j < 4; j++) Wl4[j * 256 + t] = Wg4[j * 256 + t];

  // stage: 64 rows x 128 ch of bf16 (uint4 = 8 ch), convert + bias + elu.
  // out1_bf row = 64 uints; q covers channels q*8..q*8+7 -> uint offset q*4.  (R4 bug: was gr*32+q*2)
  #pragma unroll
  for (int j = 0; j < 4; j++){
    int fi = j * 256 + t;               // 0..1023
    int row = fi >> 4, q = fi & 15;     // q: 8-channel group
    int gr = rb + row;
    float v[8] = {0.f,0.f,0.f,0.f,0.f,0.f,0.f,0.f};
    if (gr < N){
      uint4 u = *(const uint4*)&out1_bf[(size_t)gr * 64 + q * 4];
      float4 bva = *(const float4*)&b1[q * 8];
      float4 bvb = *(const float4*)&b1[q * 8 + 4];
      v[0] = elu_f(bf2f((unsigned short)(u.x & 0xffff)) + bva.x);
      v[1] = elu_f(bf2f((unsigned short)(u.x >> 16))    + bva.y);
      v[2] = elu_f(bf2f((unsigned short)(u.y & 0xffff)) + bva.z);
      v[3] = elu_f(bf2f((unsigned short)(u.y >> 16))    + bva.w);
      v[4] = elu_f(bf2f((unsigned short)(u.z & 0xffff)) + bvb.x);
      v[5] = elu_f(bf2f((unsigned short)(u.z >> 16))    + bvb.y);
      v[6] = elu_f(bf2f((unsigned short)(u.w & 0xffff)) + bvb.z);
      v[7] = elu_f(bf2f((unsigned short)(u.w >> 16))    + bvb.w);
    }
    #pragma unroll
    for (int i = 0; i < 8; i++) Xl[row * 132 + q * 8 + i] = v[i];
  }
  __syncthreads();

  int cg = t & 7, rg = t >> 3;
  int c0 = cg * 4, r0 = rg * 2;
  float acc[2][4] = {};

  #pragma unroll 8
  for (int k = 0; k < 128; k++){
    float a0 = Xl[r0 * 132 + k];
    float a1 = Xl[(r0 + 1) * 132 + k];
    float4 b = *(float4*)&Wl[k * 32 + c0];
    acc[0][0] += a0 * b.x; acc[0][1] += a0 * b.y; acc[0][2] += a0 * b.z; acc[0][3] += a0 * b.w;
    acc[1][0] += a1 * b.x; acc[1][1] += a1 * b.y; acc[1][2] += a1 * b.z; acc[1][3] += a1 * b.w;
  }

  float as[4], ad[4];
  #pragma unroll
  for (int j = 0; j < 4; j++){ as[j] = a_src[c0 + j]; ad[j] = a_dst[c0 + j]; }
  #pragma unroll
  for (int i = 0; i < 2; i++){
    int row = rb + r0 + i;
    if (row < N){
      ushort4 o;
      o.x = f2bf(acc[i][0]); o.y = f2bf(acc[i][1]); o.z = f2bf(acc[i][2]); o.w = f2bf(acc[i][3]);
      *(ushort4*)&h2_bf[(size_t)row * 32 + c0] = o;
    }
    float ps = 0.f, pd = 0.f;
    #pragma unroll
    for (int j = 0; j < 4; j++){ ps += acc[i][j] * as[j]; pd += acc[i][j] * ad[j]; }
    ps += __shfl_xor(ps, 1, 8); ps += __shfl_xor(ps, 2, 8); ps += __shfl_xor(ps, 4, 8);
    pd += __shfl_xor(pd, 1, 8); pd += __shfl_xor(pd, 2, 8); pd += __shfl_xor(pd, 4, 8);
    if ((t & 7) == 0 && row < N){ s_src2[row] = ps; s_dst2[row] = pd; }
  }
}

// ---------------- agg2: 8 nodes/block (32 ch each), fused weights (1 exp per lane per 4 edges)
__global__ __launch_bounds__(256) void k_agg2(
    const int* __restrict__ row_ptr, const int* __restrict__ csr_src,
    const float* __restrict__ ss2, const float* __restrict__ sd2,
    const unsigned short* __restrict__ h2bf, const float* __restrict__ b2,
    float* __restrict__ out, int N){
  int n = blockIdx.x * 8 + (threadIdx.x >> 5);
  if (n >= N) return;
  int c = threadIdx.x & 31;
  float sdv = sd2[n];
  int beg = row_ptr[n], end = row_ptr[n + 1];
  float acc = 0.f, sw = 0.f;
  int e = beg;
  for (; e + 4 <= end; e += 4){
    int s0 = csr_src[e], s1 = csr_src[e+1], s2 = csr_src[e+2], s3 = csr_src[e+3];
    int sj = csr_src[e + (c & 3)];
    float wv = __expf(lrelu(ss2[sj] + sdv));
    float w0 = __shfl(wv, 0, 4), w1 = __shfl(wv, 1, 4);
    float w2 = __shfl(wv, 2, 4), w3 = __shfl(wv, 3, 4);
    float v0 = bf2f(h2bf[(size_t)s0 * 32 + c]);
    float v1 = bf2f(h2bf[(size_t)s1 * 32 + c]);
    float v2 = bf2f(h2bf[(size_t)s2 * 32 + c]);
    float v3 = bf2f(h2bf[(size_t)s3 * 32 + c]);
    acc += w0*v0 + w1*v1 + w2*v2 + w3*v3;
    sw += w0 + w1 + w2 + w3;
  }
  for (; e < end; e++){
    int s = csr_src[e];
    float w = __expf(lrelu(ss2[s] + sdv));
    acc += w * bf2f(h2bf[(size_t)s * 32 + c]);
    sw += w;
  }
  out[(size_t)n * 32 + c] = acc / (sw + 1e-16f) + b2[c];
}

extern "C" void kernel_launch(void* const* d_in, const int* in_sizes, int n_in,
                              void* d_out, int out_size, void* d_ws, size_t ws_size,
                              hipStream_t stream) {
  const float* x      = (const float*)d_in[0];
  const int*   ei     = (const int*)  d_in[1];
  const float* W1     = (const float*)d_in[2];
  const float* a_src1 = (const float*)d_in[3];
  const float* a_dst1 = (const float*)d_in[4];
  const float* b1     = (const float*)d_in[5];
  const float* W2     = (const float*)d_in[6];
  const float* a_src2 = (const float*)d_in[7];
  const float* a_dst2 = (const float*)d_in[8];
  const float* b2     = (const float*)d_in[9];
  float* out = (float*)d_out;

  int N = in_sizes[0] / 128;
  int E = in_sizes[1] / 2;
  const int* srcp = ei;
  const int* dstp = ei + E;
  int total = E + N;

  char* p = (char*)d_ws;
  auto alloc = [&](size_t bytes) -> void* {
    void* r = (void*)p; p += (bytes + 255) & ~(size_t)255; return r;
  };
  unsigned short* h_bf   = (unsigned short*)alloc((size_t)N * 128 * 2);
  unsigned int*   out1_bf = (unsigned int*)alloc((size_t)N * 64 * 4);   // 128 bf16/row packed as 64 uint
  unsigned short* h2_bf  = (unsigned short*)alloc((size_t)N * 32 * 2);
  float* ss1  = (float*)alloc((size_t)N * 4 * 4);
  float* sd1  = (float*)alloc((size_t)N * 4 * 4);
  float* ss2  = (float*)alloc((size_t)N * 4);
  float* sd2  = (float*)alloc((size_t)N * 4);
  int* rank   = (int*)alloc((size_t)E * 4);
  int* deg    = (int*)alloc((size_t)N * 4);
  int* rowp   = (int*)alloc((size_t)(N + 1) * 4);
  int* csr    = (int*)alloc((size_t)total * 4);
  int* parts  = (int*)alloc(256 * 4);
  (void)ws_size; (void)n_in; (void)out_size;

  hipMemsetAsync(deg, 0, (size_t)N * 4, stream);
  k_count<<<(E + 255) / 256, 256, 0, stream>>>(dstp, E, deg, rank);
  int NB = (N + 1023) / 1024;
  k_scan1<<<NB, 256, 0, stream>>>(deg, rowp, parts, N);
  k_scan2<<<1, 128, 0, stream>>>(parts, NB);
  k_scan3<<<(N + 255) / 256, 256, 0, stream>>>(rowp, parts, N, total);
  k_scatter<<<(total + 255) / 256, 256, 0, stream>>>(srcp, dstp, rank, deg, rowp, E, N, csr);

  k_gemm1<<<(N + 63) / 64, 256, 0, stream>>>(x, W1, a_src1, a_dst1, h_bf, ss1, sd1, N);
  k_agg1<<<(N + 3) / 4, 256, 0, stream>>>(rowp, csr, ss1, sd1, (const __hip_bfloat162*)h_bf, out1_bf, N);
  k_gemm2<<<(N + 63) / 64, 256, 0, stream>>>(out1_bf, b1, W2, a_src2, a_dst2, h2_bf, ss2, sd2, N);
  k_agg2<<<(N + 7) / 8, 256, 0, stream>>>(rowp, csr, ss2, sd2, h2_bf, b2, out, N);
}

// Round 6
// 367.229 us; speedup vs baseline: 5.2021x; 1.0977x over previous
//
#include <hip/hip_runtime.h>
#include <hip/hip_bf16.h>

#define NEG 0.2f
#define BK_SHIFT 9       // 512 nodes per bucket
#define BK_CAP 9216      // slots per bucket (mean ~8192, sigma ~90 -> 11 sigma headroom)

__device__ __forceinline__ float lrelu(float x){ return x > 0.f ? x : NEG * x; }
__device__ __forceinline__ float elu_f(float x){ return x > 0.f ? x : expm1f(x); }
__device__ __forceinline__ unsigned short f2bf(float f){
  unsigned int u = __float_as_uint(f);
  unsigned int r = u + 0x7fffu + ((u >> 16) & 1u);   // round-to-nearest-even
  return (unsigned short)(r >> 16);
}
__device__ __forceinline__ float bf2f(unsigned short u){
  return __uint_as_float(((unsigned int)u) << 16);
}

// ---------------- CSR build: bucket-major binning (kills random 4B write-allocate) ----------------
// Phase A: bin edges (src,dst) into bucket-major ebuf. Per-block LDS histogram,
// one global atomic per (block,bucket), placement via LDS cursors -> writes land in
// contiguous ~cnt*8B runs per bucket.
__global__ __launch_bounds__(256) void k_binA(
    const int* __restrict__ src, const int* __restrict__ dst, int E,
    int* __restrict__ gcursor, int2* __restrict__ ebuf){
  __shared__ int hist[256];
  __shared__ int base[256];
  int t = threadIdx.x;
  hist[t] = 0;
  __syncthreads();
  int e0 = blockIdx.x * 4096;
  for (int j = 0; j < 16; j++){
    int e = e0 + j * 256 + t;
    if (e < E) atomicAdd(&hist[dst[e] >> BK_SHIFT], 1);
  }
  __syncthreads();
  int cnt = hist[t];
  if (cnt > 0) base[t] = atomicAdd(&gcursor[t], cnt);
  hist[t] = 0;                   // reuse as local placement cursor
  __syncthreads();
  for (int j = 0; j < 16; j++){
    int e = e0 + j * 256 + t;
    if (e < E){
      int d = dst[e]; int b = d >> BK_SHIFT;
      int loc = atomicAdd(&hist[b], 1);
      ebuf[(size_t)b * BK_CAP + base[b] + loc] = make_int2(src[e], d);
    }
  }
}

// Phase B1: per-bucket degree count via LDS histogram (no global atomics)
__global__ __launch_bounds__(256) void k_degB(
    const int2* __restrict__ ebuf, const int* __restrict__ gcount,
    int* __restrict__ deg, int N){
  __shared__ int ld[512];
  int b = blockIdx.x, t = threadIdx.x;
  ld[t] = 0; ld[t + 256] = 0;
  __syncthreads();
  int cnt = gcount[b];
  int nbase = b << BK_SHIFT;
  const int2* eb = ebuf + (size_t)b * BK_CAP;
  for (int i = t; i < cnt; i += 256)
    atomicAdd(&ld[eb[i].y - nbase], 1);
  __syncthreads();
  int n0 = nbase + t;
  if (n0 < N) deg[n0] = ld[t];
  int n1 = nbase + 256 + t;
  if (n1 < N) deg[n1] = ld[t + 256];
}

__global__ void k_scan1(const int* __restrict__ deg, int* row_ptr, int* partials, int N){
  __shared__ int sd[256];
  int t = threadIdx.x;
  int base = blockIdx.x * 1024 + t * 4;
  int v[4]; int s = 0;
  #pragma unroll
  for (int j = 0; j < 4; j++){ int i = base + j; v[j] = (i < N) ? (deg[i] + 1) : 0; s += v[j]; }
  sd[t] = s; __syncthreads();
  for (int off = 1; off < 256; off <<= 1){
    int x = (t >= off) ? sd[t - off] : 0;
    __syncthreads(); sd[t] += x; __syncthreads();
  }
  int pre = (t > 0) ? sd[t - 1] : 0;
  #pragma unroll
  for (int j = 0; j < 4; j++){ int i = base + j; if (i < N) row_ptr[i] = pre; pre += v[j]; }
  if (t == 255) partials[blockIdx.x] = sd[255];
}

__global__ void k_scan2(int* partials, int NB){
  __shared__ int sd[128];
  int t = threadIdx.x;
  int v = (t < NB) ? partials[t] : 0;
  sd[t] = v; __syncthreads();
  for (int off = 1; off < 128; off <<= 1){
    int x = (t >= off) ? sd[t - off] : 0;
    __syncthreads(); sd[t] += x; __syncthreads();
  }
  if (t < NB) partials[t] = sd[t] - v;   // exclusive
}

__global__ void k_scan3(int* row_ptr, const int* __restrict__ partials, int N, int total){
  int i = blockIdx.x * blockDim.x + threadIdx.x;
  if (i < N){ int r = row_ptr[i] + partials[i >> 10]; row_ptr[i] = r; }
  if (i == 0) row_ptr[N] = total;
}

// Phase B2: per-bucket csr write. Bucket's csr span is a compact contiguous region
// -> full lines dirtied, no write-allocate blowup. Self-loop = final cursor slot.
__global__ __launch_bounds__(256) void k_csrB(
    const int2* __restrict__ ebuf, const int* __restrict__ gcount,
    const int* __restrict__ rowp, int* __restrict__ csr, int N){
  __shared__ int cur[512];
  int b = blockIdx.x, t = threadIdx.x;
  int nbase = b << BK_SHIFT;
  int n0 = nbase + t;
  int n1 = nbase + 256 + t;
  cur[t]       = (n0 < N) ? rowp[n0] : 0;
  cur[t + 256] = (n1 < N) ? rowp[n1] : 0;
  __syncthreads();
  int cnt = gcount[b];
  const int2* eb = ebuf + (size_t)b * BK_CAP;
  for (int i = t; i < cnt; i += 256){
    int2 e = eb[i];
    int pos = atomicAdd(&cur[e.y - nbase], 1);
    csr[pos] = e.x;
  }
  __syncthreads();
  if (n0 < N) csr[cur[t]] = n0;          // self-loops at rowp[n]+deg[n]
  if (n1 < N) csr[cur[t + 256]] = n1;
}

// ---------------- GEMM1: x[N,128] @ W[128,128] -> h_bf[N,128] (bf16), + s_src1/s_dst1[N,4]
// 64 rows x 128 cols per block, K-chunked by 32, X transposed in LDS. 4x8 microtile.
// NO float4 arrays in the hot loop (R2's float4 a[4] + ternary spilled to scratch: 4.5 GB traffic).
__global__ __launch_bounds__(256, 4) void k_gemm1(
    const float* __restrict__ x, const float* __restrict__ W,
    const float* __restrict__ a_src, const float* __restrict__ a_dst,
    unsigned short* __restrict__ h_bf, float* __restrict__ s_src, float* __restrict__ s_dst, int N){
  __shared__ __align__(16) float Xt[32 * 68];    // [kk][row], stride 68
  __shared__ __align__(16) float Wl[32 * 128];   // [kk][col]
  int t = threadIdx.x;
  int rb = blockIdx.x * 64;

  int cg = t & 15, rg = t >> 4;
  int c0 = cg * 8, r0 = rg * 4;

  float acc[4][8] = {};

  for (int ko = 0; ko < 128; ko += 32){
    #pragma unroll
    for (int j = 0; j < 4; j++){
      int fi = j * 256 + t;
      int kr = fi >> 5, c4 = fi & 31;
      float4 w = *(const float4*)&W[(size_t)(ko + kr) * 128 + c4 * 4];
      *(float4*)&Wl[kr * 128 + c4 * 4] = w;
    }
    #pragma unroll
    for (int j = 0; j < 2; j++){
      int fi = j * 256 + t;
      int row = fi >> 3, c4 = fi & 7;
      int gr = rb + row;
      float4 v = make_float4(0.f, 0.f, 0.f, 0.f);
      if (gr < N) v = *(const float4*)&x[(size_t)gr * 128 + ko + c4 * 4];
      int kb = c4 * 4;
      Xt[(kb + 0) * 68 + row] = v.x;
      Xt[(kb + 1) * 68 + row] = v.y;
      Xt[(kb + 2) * 68 + row] = v.z;
      Xt[(kb + 3) * 68 + row] = v.w;
    }
    __syncthreads();

    #pragma unroll 8
    for (int kk = 0; kk < 32; kk++){
      float4 a  = *(float4*)&Xt[kk * 68 + r0];
      float4 b0 = *(float4*)&Wl[kk * 128 + c0];
      float4 b1 = *(float4*)&Wl[kk * 128 + c0 + 4];
      float ar0 = a.x, ar1 = a.y, ar2 = a.z, ar3 = a.w;
      acc[0][0] += ar0 * b0.x; acc[0][1] += ar0 * b0.y; acc[0][2] += ar0 * b0.z; acc[0][3] += ar0 * b0.w;
      acc[0][4] += ar0 * b1.x; acc[0][5] += ar0 * b1.y; acc[0][6] += ar0 * b1.z; acc[0][7] += ar0 * b1.w;
      acc[1][0] += ar1 * b0.x; acc[1][1] += ar1 * b0.y; acc[1][2] += ar1 * b0.z; acc[1][3] += ar1 * b0.w;
      acc[1][4] += ar1 * b1.x; acc[1][5] += ar1 * b1.y; acc[1][6] += ar1 * b1.z; acc[1][7] += ar1 * b1.w;
      acc[2][0] += ar2 * b0.x; acc[2][1] += ar2 * b0.y; acc[2][2] += ar2 * b0.z; acc[2][3] += ar2 * b0.w;
      acc[2][4] += ar2 * b1.x; acc[2][5] += ar2 * b1.y; acc[2][6] += ar2 * b1.z; acc[2][7] += ar2 * b1.w;
      acc[3][0] += ar3 * b0.x; acc[3][1] += ar3 * b0.y; acc[3][2] += ar3 * b0.z; acc[3][3] += ar3 * b0.w;
      acc[3][4] += ar3 * b1.x; acc[3][5] += ar3 * b1.y; acc[3][6] += ar3 * b1.z; acc[3][7] += ar3 * b1.w;
    }
    __syncthreads();
  }

  int head = cg >> 2;
  float as[8], ad[8];
  #pragma unroll
  for (int j = 0; j < 8; j++){ as[j] = a_src[c0 + j]; ad[j] = a_dst[c0 + j]; }
  #pragma unroll
  for (int i = 0; i < 4; i++){
    int row = rb + r0 + i;
    bool ok = row < N;
    if (ok){
      ushort4 o0, o1;
      o0.x = f2bf(acc[i][0]); o0.y = f2bf(acc[i][1]); o0.z = f2bf(acc[i][2]); o0.w = f2bf(acc[i][3]);
      o1.x = f2bf(acc[i][4]); o1.y = f2bf(acc[i][5]); o1.z = f2bf(acc[i][6]); o1.w = f2bf(acc[i][7]);
      *(ushort4*)&h_bf[(size_t)row * 128 + c0]     = o0;
      *(ushort4*)&h_bf[(size_t)row * 128 + c0 + 4] = o1;
    }
    float ps = 0.f, pd = 0.f;
    #pragma unroll
    for (int j = 0; j < 8; j++){ ps += acc[i][j] * as[j]; pd += acc[i][j] * ad[j]; }
    ps += __shfl_xor(ps, 1, 4); ps += __shfl_xor(ps, 2, 4);
    pd += __shfl_xor(pd, 1, 4); pd += __shfl_xor(pd, 2, 4);
    if ((t & 3) == 0 && ok){ s_src[(size_t)row * 4 + head] = ps; s_dst[(size_t)row * 4 + head] = pd; }
  }
}

// ---------------- agg1: 1 wave per node; weights computed once per (edge,head) and
// shuffle-broadcast (16 lanes/head were computing identical exp before) ----------------
__global__ __launch_bounds__(256) void k_agg1(
    const int* __restrict__ row_ptr, const int* __restrict__ csr_src,
    const float* __restrict__ ss, const float* __restrict__ sdst,
    const __hip_bfloat162* __restrict__ hb2,
    unsigned int* __restrict__ out1_bf, int N){
  int n = blockIdx.x * 4 + (threadIdx.x >> 6);
  if (n >= N) return;
  int l = threadIdx.x & 63;
  int hd = l >> 4;                 // this lane's head (channels 2l, 2l+1)
  int j4 = l & 3;                  // edge sub-index this lane computes a weight for
  int hh = (l >> 2) & 3;           // head this lane computes a weight for
  float swv = sdst[(size_t)n * 4 + hh];
  float sdv = sdst[(size_t)n * 4 + hd];
  int beg = row_ptr[n], end = row_ptr[n + 1];
  float ax = 0.f, ay = 0.f, sw = 0.f;
  int e = beg;
  for (; e + 4 <= end; e += 4){
    int sj = csr_src[e + j4];
    float wv = __expf(lrelu(ss[(size_t)sj * 4 + hh] + swv));
    int s0 = __shfl(sj, 0, 4), s1 = __shfl(sj, 1, 4);
    int s2 = __shfl(sj, 2, 4), s3 = __shfl(sj, 3, 4);
    float w0 = __shfl(wv, hd * 4 + 0, 16), w1 = __shfl(wv, hd * 4 + 1, 16);
    float w2 = __shfl(wv, hd * 4 + 2, 16), w3 = __shfl(wv, hd * 4 + 3, 16);
    float2 v0 = __bfloat1622float2(hb2[(size_t)s0 * 64 + l]);
    float2 v1 = __bfloat1622float2(hb2[(size_t)s1 * 64 + l]);
    float2 v2 = __bfloat1622float2(hb2[(size_t)s2 * 64 + l]);
    float2 v3 = __bfloat1622float2(hb2[(size_t)s3 * 64 + l]);
    ax += w0*v0.x + w1*v1.x + w2*v2.x + w3*v3.x;
    ay += w0*v0.y + w1*v1.y + w2*v2.y + w3*v3.y;
    sw += w0 + w1 + w2 + w3;
  }
  for (; e < end; e++){
    int s = csr_src[e];
    float w = __expf(lrelu(ss[(size_t)s * 4 + hd] + sdv));
    float2 v = __bfloat1622float2(hb2[(size_t)s * 64 + l]);
    ax += w*v.x; ay += w*v.y; sw += w;
  }
  float inv = 1.f / (sw + 1e-16f);
  unsigned int lo = f2bf(ax * inv), hi = f2bf(ay * inv);
  out1_bf[(size_t)n * 64 + l] = (hi << 16) | lo;
}

// ---------------- GEMM2: elu(out1_bf+b1)[N,128] @ W2[128,32] -> h2_bf[N,32], + s_src2/s_dst2[N]
__global__ __launch_bounds__(256) void k_gemm2(
    const unsigned int* __restrict__ out1_bf, const float* __restrict__ b1,
    const float* __restrict__ W2,
    const float* __restrict__ a_src, const float* __restrict__ a_dst,
    unsigned short* __restrict__ h2_bf, float* __restrict__ s_src2, float* __restrict__ s_dst2, int N){
  __shared__ __align__(16) float Wl[128 * 32];
  __shared__ __align__(16) float Xl[64 * 132];
  int t = threadIdx.x;
  int rb = blockIdx.x * 64;

  const float4* Wg4 = (const float4*)W2;
  float4* Wl4 = (float4*)Wl;
  #pragma unroll
  for (int j = 0; j < 4; j++) Wl4[j * 256 + t] = Wg4[j * 256 + t];

  // out1_bf row = 64 uints; q covers channels q*8..q*8+7 -> uint offset q*4
  #pragma unroll
  for (int j = 0; j < 4; j++){
    int fi = j * 256 + t;               // 0..1023
    int row = fi >> 4, q = fi & 15;     // q: 8-channel group
    int gr = rb + row;
    float v[8] = {0.f,0.f,0.f,0.f,0.f,0.f,0.f,0.f};
    if (gr < N){
      uint4 u = *(const uint4*)&out1_bf[(size_t)gr * 64 + q * 4];
      float4 bva = *(const float4*)&b1[q * 8];
      float4 bvb = *(const float4*)&b1[q * 8 + 4];
      v[0] = elu_f(bf2f((unsigned short)(u.x & 0xffff)) + bva.x);
      v[1] = elu_f(bf2f((unsigned short)(u.x >> 16))    + bva.y);
      v[2] = elu_f(bf2f((unsigned short)(u.y & 0xffff)) + bva.z);
      v[3] = elu_f(bf2f((unsigned short)(u.y >> 16))    + bva.w);
      v[4] = elu_f(bf2f((unsigned short)(u.z & 0xffff)) + bvb.x);
      v[5] = elu_f(bf2f((unsigned short)(u.z >> 16))    + bvb.y);
      v[6] = elu_f(bf2f((unsigned short)(u.w & 0xffff)) + bvb.z);
      v[7] = elu_f(bf2f((unsigned short)(u.w >> 16))    + bvb.w);
    }
    #pragma unroll
    for (int i = 0; i < 8; i++) Xl[row * 132 + q * 8 + i] = v[i];
  }
  __syncthreads();

  int cg = t & 7, rg = t >> 3;
  int c0 = cg * 4, r0 = rg * 2;
  float acc[2][4] = {};

  #pragma unroll 8
  for (int k = 0; k < 128; k++){
    float a0 = Xl[r0 * 132 + k];
    float a1 = Xl[(r0 + 1) * 132 + k];
    float4 b = *(float4*)&Wl[k * 32 + c0];
    acc[0][0] += a0 * b.x; acc[0][1] += a0 * b.y; acc[0][2] += a0 * b.z; acc[0][3] += a0 * b.w;
    acc[1][0] += a1 * b.x; acc[1][1] += a1 * b.y; acc[1][2] += a1 * b.z; acc[1][3] += a1 * b.w;
  }

  float as[4], ad[4];
  #pragma unroll
  for (int j = 0; j < 4; j++){ as[j] = a_src[c0 + j]; ad[j] = a_dst[c0 + j]; }
  #pragma unroll
  for (int i = 0; i < 2; i++){
    int row = rb + r0 + i;
    if (row < N){
      ushort4 o;
      o.x = f2bf(acc[i][0]); o.y = f2bf(acc[i][1]); o.z = f2bf(acc[i][2]); o.w = f2bf(acc[i][3]);
      *(ushort4*)&h2_bf[(size_t)row * 32 + c0] = o;
    }
    float ps = 0.f, pd = 0.f;
    #pragma unroll
    for (int j = 0; j < 4; j++){ ps += acc[i][j] * as[j]; pd += acc[i][j] * ad[j]; }
    ps += __shfl_xor(ps, 1, 8); ps += __shfl_xor(ps, 2, 8); ps += __shfl_xor(ps, 4, 8);
    pd += __shfl_xor(pd, 1, 8); pd += __shfl_xor(pd, 2, 8); pd += __shfl_xor(pd, 4, 8);
    if ((t & 7) == 0 && row < N){ s_src2[row] = ps; s_dst2[row] = pd; }
  }
}

// ---------------- agg2: 8 nodes/block (32 ch each), fused weights (1 exp per lane per 4 edges)
__global__ __launch_bounds__(256) void k_agg2(
    const int* __restrict__ row_ptr, const int* __restrict__ csr_src,
    const float* __restrict__ ss2, const float* __restrict__ sd2,
    const unsigned short* __restrict__ h2bf, const float* __restrict__ b2,
    float* __restrict__ out, int N){
  int n = blockIdx.x * 8 + (threadIdx.x >> 5);
  if (n >= N) return;
  int c = threadIdx.x & 31;
  float sdv = sd2[n];
  int beg = row_ptr[n], end = row_ptr[n + 1];
  float acc = 0.f, sw = 0.f;
  int e = beg;
  for (; e + 4 <= end; e += 4){
    int s0 = csr_src[e], s1 = csr_src[e+1], s2 = csr_src[e+2], s3 = csr_src[e+3];
    int sj = csr_src[e + (c & 3)];
    float wv = __expf(lrelu(ss2[sj] + sdv));
    float w0 = __shfl(wv, 0, 4), w1 = __shfl(wv, 1, 4);
    float w2 = __shfl(wv, 2, 4), w3 = __shfl(wv, 3, 4);
    float v0 = bf2f(h2bf[(size_t)s0 * 32 + c]);
    float v1 = bf2f(h2bf[(size_t)s1 * 32 + c]);
    float v2 = bf2f(h2bf[(size_t)s2 * 32 + c]);
    float v3 = bf2f(h2bf[(size_t)s3 * 32 + c]);
    acc += w0*v0 + w1*v1 + w2*v2 + w3*v3;
    sw += w0 + w1 + w2 + w3;
  }
  for (; e < end; e++){
    int s = csr_src[e];
    float w = __expf(lrelu(ss2[s] + sdv));
    acc += w * bf2f(h2bf[(size_t)s * 32 + c]);
    sw += w;
  }
  out[(size_t)n * 32 + c] = acc / (sw + 1e-16f) + b2[c];
}

extern "C" void kernel_launch(void* const* d_in, const int* in_sizes, int n_in,
                              void* d_out, int out_size, void* d_ws, size_t ws_size,
                              hipStream_t stream) {
  const float* x      = (const float*)d_in[0];
  const int*   ei     = (const int*)  d_in[1];
  const float* W1     = (const float*)d_in[2];
  const float* a_src1 = (const float*)d_in[3];
  const float* a_dst1 = (const float*)d_in[4];
  const float* b1     = (const float*)d_in[5];
  const float* W2     = (const float*)d_in[6];
  const float* a_src2 = (const float*)d_in[7];
  const float* a_dst2 = (const float*)d_in[8];
  const float* b2     = (const float*)d_in[9];
  float* out = (float*)d_out;

  int N = in_sizes[0] / 128;
  int E = in_sizes[1] / 2;
  const int* srcp = ei;
  const int* dstp = ei + E;
  int total = E + N;
  int NBK = (N + 511) >> 9;       // buckets of 512 nodes

  char* p = (char*)d_ws;
  auto alloc = [&](size_t bytes) -> void* {
    void* r = (void*)p; p += (bytes + 255) & ~(size_t)255; return r;
  };
  unsigned short* h_bf    = (unsigned short*)alloc((size_t)N * 128 * 2);
  unsigned int*   out1_bf = (unsigned int*)alloc((size_t)N * 64 * 4);   // 128 bf16/row packed as 64 uint
  unsigned short* h2_bf   = (unsigned short*)alloc((size_t)N * 32 * 2);
  float* ss1  = (float*)alloc((size_t)N * 4 * 4);
  float* sd1  = (float*)alloc((size_t)N * 4 * 4);
  float* ss2  = (float*)alloc((size_t)N * 4);
  float* sd2  = (float*)alloc((size_t)N * 4);
  int* deg    = (int*)alloc((size_t)N * 4);
  int* rowp   = (int*)alloc((size_t)(N + 1) * 4);
  int* csr    = (int*)alloc((size_t)total * 4);
  int* parts  = (int*)alloc(256 * 4);
  int* gcur   = (int*)alloc(256 * 4);
  // ebuf (bucket staging, 196*9216*8 = 14.5 MB) aliases out1_bf (25.6 MB):
  // lifetimes disjoint (ebuf: binA..csrB; out1_bf: agg1..gemm2)
  int2* ebuf  = (int2*)out1_bf;
  (void)ws_size; (void)n_in; (void)out_size;

  hipMemsetAsync(gcur, 0, 256 * 4, stream);
  k_binA<<<(E + 4095) / 4096, 256, 0, stream>>>(srcp, dstp, E, gcur, ebuf);
  k_degB<<<NBK, 256, 0, stream>>>(ebuf, gcur, deg, N);
  int NB = (N + 1023) / 1024;
  k_scan1<<<NB, 256, 0, stream>>>(deg, rowp, parts, N);
  k_scan2<<<1, 128, 0, stream>>>(parts, NB);
  k_scan3<<<(N + 255) / 256, 256, 0, stream>>>(rowp, parts, N, total);
  k_csrB<<<NBK, 256, 0, stream>>>(ebuf, gcur, rowp, csr, N);

  k_gemm1<<<(N + 63) / 64, 256, 0, stream>>>(x, W1, a_src1, a_dst1, h_bf, ss1, sd1, N);
  k_agg1<<<(N + 3) / 4, 256, 0, stream>>>(rowp, csr, ss1, sd1, (const __hip_bfloat162*)h_bf, out1_bf, N);
  k_gemm2<<<(N + 63) / 64, 256, 0, stream>>>(out1_bf, b1, W2, a_src2, a_dst2, h2_bf, ss2, sd2, N);
  k_agg2<<<(N + 7) / 8, 256, 0, stream>>>(rowp, csr, ss2, sd2, h2_bf, b2, out, N);
}

// Round 7
// 344.806 us; speedup vs baseline: 5.5404x; 1.0650x over previous
//
#include <hip/hip_runtime.h>
#include <hip/hip_bf16.h>

#define NEG 0.2f
#define BK_SHIFT 9       // 512 nodes per bucket
#define BK_CAP 9216      // slots per bucket (mean ~8192, sigma ~90 -> 11 sigma headroom)

typedef short short8 __attribute__((ext_vector_type(8)));   // 8 bf16 (4 VGPRs)
typedef float f32x4 __attribute__((ext_vector_type(4)));

__device__ __forceinline__ float lrelu(float x){ return x > 0.f ? x : NEG * x; }
__device__ __forceinline__ float elu_f(float x){ return x > 0.f ? x : expm1f(x); }
__device__ __forceinline__ unsigned short f2bf(float f){
  unsigned int u = __float_as_uint(f);
  unsigned int r = u + 0x7fffu + ((u >> 16) & 1u);   // round-to-nearest-even
  return (unsigned short)(r >> 16);
}
__device__ __forceinline__ float bf2f(unsigned short u){
  return __uint_as_float(((unsigned int)u) << 16);
}

// ---------------- CSR build: bucket-major binning (kills random 4B write-allocate) ----------------
__global__ __launch_bounds__(256) void k_binA(
    const int* __restrict__ src, const int* __restrict__ dst, int E,
    int* __restrict__ gcursor, int2* __restrict__ ebuf){
  __shared__ int hist[256];
  __shared__ int base[256];
  int t = threadIdx.x;
  hist[t] = 0;
  __syncthreads();
  int e0 = blockIdx.x * 4096;
  for (int j = 0; j < 16; j++){
    int e = e0 + j * 256 + t;
    if (e < E) atomicAdd(&hist[dst[e] >> BK_SHIFT], 1);
  }
  __syncthreads();
  int cnt = hist[t];
  if (cnt > 0) base[t] = atomicAdd(&gcursor[t], cnt);
  hist[t] = 0;                   // reuse as local placement cursor
  __syncthreads();
  for (int j = 0; j < 16; j++){
    int e = e0 + j * 256 + t;
    if (e < E){
      int d = dst[e]; int b = d >> BK_SHIFT;
      int loc = atomicAdd(&hist[b], 1);
      ebuf[(size_t)b * BK_CAP + base[b] + loc] = make_int2(src[e], d);
    }
  }
}

__global__ __launch_bounds__(256) void k_degB(
    const int2* __restrict__ ebuf, const int* __restrict__ gcount,
    int* __restrict__ deg, int N){
  __shared__ int ld[512];
  int b = blockIdx.x, t = threadIdx.x;
  ld[t] = 0; ld[t + 256] = 0;
  __syncthreads();
  int cnt = gcount[b];
  int nbase = b << BK_SHIFT;
  const int2* eb = ebuf + (size_t)b * BK_CAP;
  for (int i = t; i < cnt; i += 256)
    atomicAdd(&ld[eb[i].y - nbase], 1);
  __syncthreads();
  int n0 = nbase + t;
  if (n0 < N) deg[n0] = ld[t];
  int n1 = nbase + 256 + t;
  if (n1 < N) deg[n1] = ld[t + 256];
}

__global__ void k_scan1(const int* __restrict__ deg, int* row_ptr, int* partials, int N){
  __shared__ int sd[256];
  int t = threadIdx.x;
  int base = blockIdx.x * 1024 + t * 4;
  int v[4]; int s = 0;
  #pragma unroll
  for (int j = 0; j < 4; j++){ int i = base + j; v[j] = (i < N) ? (deg[i] + 1) : 0; s += v[j]; }
  sd[t] = s; __syncthreads();
  for (int off = 1; off < 256; off <<= 1){
    int x = (t >= off) ? sd[t - off] : 0;
    __syncthreads(); sd[t] += x; __syncthreads();
  }
  int pre = (t > 0) ? sd[t - 1] : 0;
  #pragma unroll
  for (int j = 0; j < 4; j++){ int i = base + j; if (i < N) row_ptr[i] = pre; pre += v[j]; }
  if (t == 255) partials[blockIdx.x] = sd[255];
}

__global__ void k_scan2(int* partials, int NB){
  __shared__ int sd[128];
  int t = threadIdx.x;
  int v = (t < NB) ? partials[t] : 0;
  sd[t] = v; __syncthreads();
  for (int off = 1; off < 128; off <<= 1){
    int x = (t >= off) ? sd[t - off] : 0;
    __syncthreads(); sd[t] += x; __syncthreads();
  }
  if (t < NB) partials[t] = sd[t] - v;   // exclusive
}

__global__ void k_scan3(int* row_ptr, const int* __restrict__ partials, int N, int total){
  int i = blockIdx.x * blockDim.x + threadIdx.x;
  if (i < N){ int r = row_ptr[i] + partials[i >> 10]; row_ptr[i] = r; }
  if (i == 0) row_ptr[N] = total;
}

__global__ __launch_bounds__(256) void k_csrB(
    const int2* __restrict__ ebuf, const int* __restrict__ gcount,
    const int* __restrict__ rowp, int* __restrict__ csr, int N){
  __shared__ int cur[512];
  int b = blockIdx.x, t = threadIdx.x;
  int nbase = b << BK_SHIFT;
  int n0 = nbase + t;
  int n1 = nbase + 256 + t;
  cur[t]       = (n0 < N) ? rowp[n0] : 0;
  cur[t + 256] = (n1 < N) ? rowp[n1] : 0;
  __syncthreads();
  int cnt = gcount[b];
  const int2* eb = ebuf + (size_t)b * BK_CAP;
  for (int i = t; i < cnt; i += 256){
    int2 e = eb[i];
    int pos = atomicAdd(&cur[e.y - nbase], 1);
    csr[pos] = e.x;
  }
  __syncthreads();
  if (n0 < N) csr[cur[t]] = n0;          // self-loops at rowp[n]+deg[n]
  if (n1 < N) csr[cur[t + 256]] = n1;
}

// ---------------- GEMM1 (MFMA bf16): x[N,128] @ W[128,128] -> h_bf[N,128] ----------------
// 64 rows x 128 cols / block; 4 waves, each 16 rows x 128 cols as 8 col-tiles of 16x16x32 MFMA.
// Layouts (guide-verified): A[m=lane&15][k=quad*8+j]; B from Wt[n][k] (W transposed in LDS);
// D: M-dim = quad*4+reg, N-dim = lane&15. LDS 52 KB -> 3 blocks/CU.
__global__ __launch_bounds__(256, 3) void k_gemm1(
    const float* __restrict__ x, const float* __restrict__ W,
    unsigned short* __restrict__ h_bf, int N){
  __shared__ unsigned short Wt[128 * 136];   // Wt[n][k], stride 136 (2-way bank alias: free)
  __shared__ unsigned short Xb[64 * 136];    // Xb[row][k], stride 136
  int t = threadIdx.x;
  int rb = blockIdx.x * 64;

  // stage W transposed as bf16: thread = (col n, k-half)
  {
    int n = t & 127, kh = (t >> 7) << 6;
    #pragma unroll
    for (int j = 0; j < 16; j++){
      int k0 = kh + j * 4;
      float w0 = W[(size_t)(k0 + 0) * 128 + n];
      float w1 = W[(size_t)(k0 + 1) * 128 + n];
      float w2 = W[(size_t)(k0 + 2) * 128 + n];
      float w3 = W[(size_t)(k0 + 3) * 128 + n];
      uint2 pk;
      pk.x = ((unsigned)f2bf(w1) << 16) | f2bf(w0);
      pk.y = ((unsigned)f2bf(w3) << 16) | f2bf(w2);
      *(uint2*)&Wt[n * 136 + k0] = pk;
    }
  }
  // stage X rows as bf16
  #pragma unroll
  for (int j = 0; j < 8; j++){
    int fi = j * 256 + t;           // 0..2047
    int row = fi >> 5, k4 = (fi & 31) * 4;
    int gr = rb + row;
    float4 v = make_float4(0.f, 0.f, 0.f, 0.f);
    if (gr < N) v = *(const float4*)&x[(size_t)gr * 128 + k4];
    uint2 pk;
    pk.x = ((unsigned)f2bf(v.y) << 16) | f2bf(v.x);
    pk.y = ((unsigned)f2bf(v.w) << 16) | f2bf(v.z);
    *(uint2*)&Xb[row * 136 + k4] = pk;
  }
  __syncthreads();

  int w = t >> 6, l = t & 63;
  int m = l & 15, quad = l >> 4;
  f32x4 acc[8];
  #pragma unroll
  for (int ct = 0; ct < 8; ct++) acc[ct] = (f32x4){0.f, 0.f, 0.f, 0.f};

  #pragma unroll
  for (int kc = 0; kc < 4; kc++){
    short8 a = *(const short8*)&Xb[(w * 16 + m) * 136 + kc * 32 + quad * 8];
    #pragma unroll
    for (int ct = 0; ct < 8; ct++){
      short8 b = *(const short8*)&Wt[(ct * 16 + m) * 136 + kc * 32 + quad * 8];
      acc[ct] = __builtin_amdgcn_mfma_f32_16x16x32_bf16(a, b, acc[ct], 0, 0, 0);
    }
  }

  #pragma unroll
  for (int reg = 0; reg < 4; reg++){
    int gr = rb + w * 16 + quad * 4 + reg;
    if (gr < N){
      #pragma unroll
      for (int ct = 0; ct < 8; ct++)
        h_bf[(size_t)gr * 128 + ct * 16 + m] = f2bf(acc[ct][reg]);
    }
  }
}

// ---------------- score1: ss/sd from h_bf (L2-warm), 4 nodes/block ----------------
__global__ __launch_bounds__(256) void k_score1(
    const unsigned int* __restrict__ hb, const float* __restrict__ a_src,
    const float* __restrict__ a_dst, float* __restrict__ ss, float* __restrict__ sd, int N){
  int n = blockIdx.x * 4 + (threadIdx.x >> 6);
  if (n >= N) return;
  int l = threadIdx.x & 63;
  unsigned int u = hb[(size_t)n * 64 + l];
  float vx = bf2f((unsigned short)(u & 0xffff));
  float vy = bf2f((unsigned short)(u >> 16));
  float ps = vx * a_src[2 * l] + vy * a_src[2 * l + 1];
  float pd = vx * a_dst[2 * l] + vy * a_dst[2 * l + 1];
  ps += __shfl_xor(ps, 1, 16); ps += __shfl_xor(ps, 2, 16);
  ps += __shfl_xor(ps, 4, 16); ps += __shfl_xor(ps, 8, 16);
  pd += __shfl_xor(pd, 1, 16); pd += __shfl_xor(pd, 2, 16);
  pd += __shfl_xor(pd, 4, 16); pd += __shfl_xor(pd, 8, 16);
  if ((l & 15) == 0){
    int hd = l >> 4;
    ss[(size_t)n * 4 + hd] = ps;
    sd[(size_t)n * 4 + hd] = pd;
  }
}

// ---------------- agg1: 1 wave per node; weights once per (edge,head), shuffle-broadcast ----
__global__ __launch_bounds__(256) void k_agg1(
    const int* __restrict__ row_ptr, const int* __restrict__ csr_src,
    const float* __restrict__ ss, const float* __restrict__ sdst,
    const __hip_bfloat162* __restrict__ hb2,
    unsigned int* __restrict__ out1_bf, int N){
  int n = blockIdx.x * 4 + (threadIdx.x >> 6);
  if (n >= N) return;
  int l = threadIdx.x & 63;
  int hd = l >> 4;                 // this lane's head (channels 2l, 2l+1)
  int j4 = l & 3;                  // edge sub-index this lane computes a weight for
  int hh = (l >> 2) & 3;           // head this lane computes a weight for
  float swv = sdst[(size_t)n * 4 + hh];
  float sdv = sdst[(size_t)n * 4 + hd];
  int beg = row_ptr[n], end = row_ptr[n + 1];
  float ax = 0.f, ay = 0.f, sw = 0.f;
  int e = beg;
  for (; e + 4 <= end; e += 4){
    int sj = csr_src[e + j4];
    float wv = __expf(lrelu(ss[(size_t)sj * 4 + hh] + swv));
    int s0 = __shfl(sj, 0, 4), s1 = __shfl(sj, 1, 4);
    int s2 = __shfl(sj, 2, 4), s3 = __shfl(sj, 3, 4);
    float w0 = __shfl(wv, hd * 4 + 0, 16), w1 = __shfl(wv, hd * 4 + 1, 16);
    float w2 = __shfl(wv, hd * 4 + 2, 16), w3 = __shfl(wv, hd * 4 + 3, 16);
    float2 v0 = __bfloat1622float2(hb2[(size_t)s0 * 64 + l]);
    float2 v1 = __bfloat1622float2(hb2[(size_t)s1 * 64 + l]);
    float2 v2 = __bfloat1622float2(hb2[(size_t)s2 * 64 + l]);
    float2 v3 = __bfloat1622float2(hb2[(size_t)s3 * 64 + l]);
    ax += w0*v0.x + w1*v1.x + w2*v2.x + w3*v3.x;
    ay += w0*v0.y + w1*v1.y + w2*v2.y + w3*v3.y;
    sw += w0 + w1 + w2 + w3;
  }
  for (; e < end; e++){
    int s = csr_src[e];
    float w = __expf(lrelu(ss[(size_t)s * 4 + hd] + sdv));
    float2 v = __bfloat1622float2(hb2[(size_t)s * 64 + l]);
    ax += w*v.x; ay += w*v.y; sw += w;
  }
  float inv = 1.f / (sw + 1e-16f);
  unsigned int lo = f2bf(ax * inv), hi = f2bf(ay * inv);
  out1_bf[(size_t)n * 64 + l] = (hi << 16) | lo;
}

// ---------------- GEMM2: elu(out1_bf+b1)[N,128] @ W2[128,32] -> h2_bf[N,32], + s_src2/s_dst2[N]
__global__ __launch_bounds__(256) void k_gemm2(
    const unsigned int* __restrict__ out1_bf, const float* __restrict__ b1,
    const float* __restrict__ W2,
    const float* __restrict__ a_src, const float* __restrict__ a_dst,
    unsigned short* __restrict__ h2_bf, float* __restrict__ s_src2, float* __restrict__ s_dst2, int N){
  __shared__ __align__(16) float Wl[128 * 32];
  __shared__ __align__(16) float Xl[64 * 132];
  int t = threadIdx.x;
  int rb = blockIdx.x * 64;

  const float4* Wg4 = (const float4*)W2;
  float4* Wl4 = (float4*)Wl;
  #pragma unroll
  for (int j = 0; j < 4; j++) Wl4[j * 256 + t] = Wg4[j * 256 + t];

  // out1_bf row = 64 uints; q covers channels q*8..q*8+7 -> uint offset q*4
  #pragma unroll
  for (int j = 0; j < 4; j++){
    int fi = j * 256 + t;               // 0..1023
    int row = fi >> 4, q = fi & 15;     // q: 8-channel group
    int gr = rb + row;
    float v[8] = {0.f,0.f,0.f,0.f,0.f,0.f,0.f,0.f};
    if (gr < N){
      uint4 u = *(const uint4*)&out1_bf[(size_t)gr * 64 + q * 4];
      float4 bva = *(const float4*)&b1[q * 8];
      float4 bvb = *(const float4*)&b1[q * 8 + 4];
      v[0] = elu_f(bf2f((unsigned short)(u.x & 0xffff)) + bva.x);
      v[1] = elu_f(bf2f((unsigned short)(u.x >> 16))    + bva.y);
      v[2] = elu_f(bf2f((unsigned short)(u.y & 0xffff)) + bva.z);
      v[3] = elu_f(bf2f((unsigned short)(u.y >> 16))    + bva.w);
      v[4] = elu_f(bf2f((unsigned short)(u.z & 0xffff)) + bvb.x);
      v[5] = elu_f(bf2f((unsigned short)(u.z >> 16))    + bvb.y);
      v[6] = elu_f(bf2f((unsigned short)(u.w & 0xffff)) + bvb.z);
      v[7] = elu_f(bf2f((unsigned short)(u.w >> 16))    + bvb.w);
    }
    #pragma unroll
    for (int i = 0; i < 8; i++) Xl[row * 132 + q * 8 + i] = v[i];
  }
  __syncthreads();

  int cg = t & 7, rg = t >> 3;
  int c0 = cg * 4, r0 = rg * 2;
  float acc[2][4] = {};

  #pragma unroll 8
  for (int k = 0; k < 128; k++){
    float a0 = Xl[r0 * 132 + k];
    float a1 = Xl[(r0 + 1) * 132 + k];
    float4 b = *(float4*)&Wl[k * 32 + c0];
    acc[0][0] += a0 * b.x; acc[0][1] += a0 * b.y; acc[0][2] += a0 * b.z; acc[0][3] += a0 * b.w;
    acc[1][0] += a1 * b.x; acc[1][1] += a1 * b.y; acc[1][2] += a1 * b.z; acc[1][3] += a1 * b.w;
  }

  float as[4], ad[4];
  #pragma unroll
  for (int j = 0; j < 4; j++){ as[j] = a_src[c0 + j]; ad[j] = a_dst[c0 + j]; }
  #pragma unroll
  for (int i = 0; i < 2; i++){
    int row = rb + r0 + i;
    if (row < N){
      ushort4 o;
      o.x = f2bf(acc[i][0]); o.y = f2bf(acc[i][1]); o.z = f2bf(acc[i][2]); o.w = f2bf(acc[i][3]);
      *(ushort4*)&h2_bf[(size_t)row * 32 + c0] = o;
    }
    float ps = 0.f, pd = 0.f;
    #pragma unroll
    for (int j = 0; j < 4; j++){ ps += acc[i][j] * as[j]; pd += acc[i][j] * ad[j]; }
    ps += __shfl_xor(ps, 1, 8); ps += __shfl_xor(ps, 2, 8); ps += __shfl_xor(ps, 4, 8);
    pd += __shfl_xor(pd, 1, 8); pd += __shfl_xor(pd, 2, 8); pd += __shfl_xor(pd, 4, 8);
    if ((t & 7) == 0 && row < N){ s_src2[row] = ps; s_dst2[row] = pd; }
  }
}

// ---------------- agg2: 8 nodes/block (32 ch each), fused weights (1 exp per lane per 4 edges)
__global__ __launch_bounds__(256) void k_agg2(
    const int* __restrict__ row_ptr, const int* __restrict__ csr_src,
    const float* __restrict__ ss2, const float* __restrict__ sd2,
    const unsigned short* __restrict__ h2bf, const float* __restrict__ b2,
    float* __restrict__ out, int N){
  int n = blockIdx.x * 8 + (threadIdx.x >> 5);
  if (n >= N) return;
  int c = threadIdx.x & 31;
  float sdv = sd2[n];
  int beg = row_ptr[n], end = row_ptr[n + 1];
  float acc = 0.f, sw = 0.f;
  int e = beg;
  for (; e + 4 <= end; e += 4){
    int s0 = csr_src[e], s1 = csr_src[e+1], s2 = csr_src[e+2], s3 = csr_src[e+3];
    int sj = csr_src[e + (c & 3)];
    float wv = __expf(lrelu(ss2[sj] + sdv));
    float w0 = __shfl(wv, 0, 4), w1 = __shfl(wv, 1, 4);
    float w2 = __shfl(wv, 2, 4), w3 = __shfl(wv, 3, 4);
    float v0 = bf2f(h2bf[(size_t)s0 * 32 + c]);
    float v1 = bf2f(h2bf[(size_t)s1 * 32 + c]);
    float v2 = bf2f(h2bf[(size_t)s2 * 32 + c]);
    float v3 = bf2f(h2bf[(size_t)s3 * 32 + c]);
    acc += w0*v0 + w1*v1 + w2*v2 + w3*v3;
    sw += w0 + w1 + w2 + w3;
  }
  for (; e < end; e++){
    int s = csr_src[e];
    float w = __expf(lrelu(ss2[s] + sdv));
    acc += w * bf2f(h2bf[(size_t)s * 32 + c]);
    sw += w;
  }
  out[(size_t)n * 32 + c] = acc / (sw + 1e-16f) + b2[c];
}

extern "C" void kernel_launch(void* const* d_in, const int* in_sizes, int n_in,
                              void* d_out, int out_size, void* d_ws, size_t ws_size,
                              hipStream_t stream) {
  const float* x      = (const float*)d_in[0];
  const int*   ei     = (const int*)  d_in[1];
  const float* W1     = (const float*)d_in[2];
  const float* a_src1 = (const float*)d_in[3];
  const float* a_dst1 = (const float*)d_in[4];
  const float* b1     = (const float*)d_in[5];
  const float* W2     = (const float*)d_in[6];
  const float* a_src2 = (const float*)d_in[7];
  const float* a_dst2 = (const float*)d_in[8];
  const float* b2     = (const float*)d_in[9];
  float* out = (float*)d_out;

  int N = in_sizes[0] / 128;
  int E = in_sizes[1] / 2;
  const int* srcp = ei;
  const int* dstp = ei + E;
  int total = E + N;
  int NBK = (N + 511) >> 9;       // buckets of 512 nodes

  char* p = (char*)d_ws;
  auto alloc = [&](size_t bytes) -> void* {
    void* r = (void*)p; p += (bytes + 255) & ~(size_t)255; return r;
  };
  unsigned short* h_bf    = (unsigned short*)alloc((size_t)N * 128 * 2);
  unsigned int*   out1_bf = (unsigned int*)alloc((size_t)N * 64 * 4);   // 128 bf16/row packed as 64 uint
  unsigned short* h2_bf   = (unsigned short*)alloc((size_t)N * 32 * 2);
  float* ss1  = (float*)alloc((size_t)N * 4 * 4);
  float* sd1  = (float*)alloc((size_t)N * 4 * 4);
  float* ss2  = (float*)alloc((size_t)N * 4);
  float* sd2  = (float*)alloc((size_t)N * 4);
  int* deg    = (int*)alloc((size_t)N * 4);
  int* rowp   = (int*)alloc((size_t)(N + 1) * 4);
  int* csr    = (int*)alloc((size_t)total * 4);
  int* parts  = (int*)alloc(256 * 4);
  int* gcur   = (int*)alloc(256 * 4);
  // ebuf (bucket staging, 196*9216*8 = 14.5 MB) aliases out1_bf (25.6 MB):
  // lifetimes disjoint (ebuf: binA..csrB; out1_bf: agg1..gemm2)
  int2* ebuf  = (int2*)out1_bf;
  (void)ws_size; (void)n_in; (void)out_size;

  hipMemsetAsync(gcur, 0, 256 * 4, stream);
  k_binA<<<(E + 4095) / 4096, 256, 0, stream>>>(srcp, dstp, E, gcur, ebuf);
  k_degB<<<NBK, 256, 0, stream>>>(ebuf, gcur, deg, N);
  int NB = (N + 1023) / 1024;
  k_scan1<<<NB, 256, 0, stream>>>(deg, rowp, parts, N);
  k_scan2<<<1, 128, 0, stream>>>(parts, NB);
  k_scan3<<<(N + 255) / 256, 256, 0, stream>>>(rowp, parts, N, total);
  k_csrB<<<NBK, 256, 0, stream>>>(ebuf, gcur, rowp, csr, N);

  k_gemm1<<<(N + 63) / 64, 256, 0, stream>>>(x, W1, h_bf, N);
  k_score1<<<(N + 3) / 4, 256, 0, stream>>>((const unsigned int*)h_bf, a_src1, a_dst1, ss1, sd1, N);
  k_agg1<<<(N + 3) / 4, 256, 0, stream>>>(rowp, csr, ss1, sd1, (const __hip_bfloat162*)h_bf, out1_bf, N);
  k_gemm2<<<(N + 63) / 64, 256, 0, stream>>>(out1_bf, b1, W2, a_src2, a_dst2, h2_bf, ss2, sd2, N);
  k_agg2<<<(N + 7) / 8, 256, 0, stream>>>(rowp, csr, ss2, sd2, h2_bf, b2, out, N);
}

// Round 8
// 331.186 us; speedup vs baseline: 5.7683x; 1.0411x over previous
//
#include <hip/hip_runtime.h>
#include <hip/hip_bf16.h>

#define NEG 0.2f
#define BK_SHIFT 9       // 512 nodes per bucket
#define BK_CAP 9216      // slots per bucket (mean ~8192, sigma ~90 -> 11 sigma headroom)

typedef short short8 __attribute__((ext_vector_type(8)));   // 8 bf16 (4 VGPRs)
typedef float f32x4 __attribute__((ext_vector_type(4)));

__device__ __forceinline__ float lrelu(float x){ return x > 0.f ? x : NEG * x; }
__device__ __forceinline__ float elu_f(float x){ return x > 0.f ? x : expm1f(x); }
__device__ __forceinline__ unsigned short f2bf(float f){
  unsigned int u = __float_as_uint(f);
  unsigned int r = u + 0x7fffu + ((u >> 16) & 1u);   // round-to-nearest-even
  return (unsigned short)(r >> 16);
}
__device__ __forceinline__ float bf2f(unsigned short u){
  return __uint_as_float(((unsigned int)u) << 16);
}

// ---------------- CSR build ----------------
// Phase A: bin edges into bucket-major ebuf (contiguous runs -> no write-allocate blowup)
__global__ __launch_bounds__(256) void k_binA(
    const int* __restrict__ src, const int* __restrict__ dst, int E,
    int* __restrict__ gcursor, int2* __restrict__ ebuf){
  __shared__ int hist[256];
  __shared__ int base[256];
  int t = threadIdx.x;
  hist[t] = 0;
  __syncthreads();
  int e0 = blockIdx.x * 4096;
  for (int j = 0; j < 16; j++){
    int e = e0 + j * 256 + t;
    if (e < E) atomicAdd(&hist[dst[e] >> BK_SHIFT], 1);
  }
  __syncthreads();
  int cnt = hist[t];
  if (cnt > 0) base[t] = atomicAdd(&gcursor[t], cnt);
  hist[t] = 0;                   // reuse as local placement cursor
  __syncthreads();
  for (int j = 0; j < 16; j++){
    int e = e0 + j * 256 + t;
    if (e < E){
      int d = dst[e]; int b = d >> BK_SHIFT;
      int loc = atomicAdd(&hist[b], 1);
      ebuf[(size_t)b * BK_CAP + base[b] + loc] = make_int2(src[e], d);
    }
  }
}

// bucket-base scan: bbase[b] = prefix of (gcount[b] + nodes_in_bucket); rowp[N]=total
__global__ __launch_bounds__(256) void k_bscan(
    const int* __restrict__ gcount, int* __restrict__ bbase,
    int* __restrict__ rowp, int N, int NBK, int total){
  __shared__ int sd[256];
  int t = threadIdx.x;
  int nodes = 0;
  if (t < NBK){ int nb = N - (t << BK_SHIFT); nodes = nb > 512 ? 512 : nb; }
  int v = (t < NBK) ? gcount[t] + nodes : 0;
  sd[t] = v; __syncthreads();
  for (int off = 1; off < 256; off <<= 1){
    int x = (t >= off) ? sd[t - off] : 0;
    __syncthreads(); sd[t] += x; __syncthreads();
  }
  if (t < NBK) bbase[t] = sd[t] - v;   // exclusive
  if (t == 0) rowp[N] = total;
}

// csrB2: per-bucket deg-histogram + LDS scan -> rowp, then placement replay (ebuf L2-warm).
// Self-loop of node n lands at rowp[n]+deg[n] (last slot), matching prior semantics.
__global__ __launch_bounds__(256) void k_csrB2(
    const int2* __restrict__ ebuf, const int* __restrict__ gcount,
    const int* __restrict__ bbase, int* __restrict__ rowp,
    int* __restrict__ csr, int N){
  __shared__ int hist[512];
  __shared__ int psum[256];
  int b = blockIdx.x, t = threadIdx.x;
  int nbase = b << BK_SHIFT;
  int cnt = gcount[b];
  const int2* eb = ebuf + (size_t)b * BK_CAP;
  hist[t] = 0; hist[t + 256] = 0;
  __syncthreads();
  for (int i = t; i < cnt; i += 256)
    atomicAdd(&hist[eb[i].y - nbase], 1);
  __syncthreads();
  int v0 = hist[2 * t], v1 = hist[2 * t + 1];
  int ps = v0 + v1;
  psum[t] = ps; __syncthreads();
  for (int off = 1; off < 256; off <<= 1){
    int x = (t >= off) ? psum[t - off] : 0;
    __syncthreads(); psum[t] += x; __syncthreads();
  }
  int eo = psum[t] - ps;               // exclusive deg-sum at element 2t
  int bb = bbase[b];
  int n0 = 2 * t, n1 = 2 * t + 1;
  int r0 = bb + eo + n0;               // +n0: one self-loop slot per prior node
  int r1 = bb + eo + v0 + n1;
  if (nbase + n0 < N) rowp[nbase + n0] = r0;
  if (nbase + n1 < N) rowp[nbase + n1] = r1;
  __syncthreads();
  hist[n0] = r0; hist[n1] = r1;        // reuse as cursors
  __syncthreads();
  for (int i = t; i < cnt; i += 256){
    int2 e = eb[i];
    int pos = atomicAdd(&hist[e.y - nbase], 1);
    csr[pos] = e.x;
  }
  __syncthreads();
  if (nbase + n0 < N) csr[hist[n0]] = nbase + n0;
  if (nbase + n1 < N) csr[hist[n1]] = nbase + n1;
}

// ---------------- GEMM1 (MFMA bf16): x[N,128] @ W[128,128] -> h_bf[N,128], + ss1/sd1 fused
// 64 rows x 128 cols / block; 4 waves, each 16 rows x 128 cols as 8 col-tiles of 16x16x32 MFMA.
// D layout: row = quad*4+reg, col = ct*16 + (lane&15); head of col tile ct = ct>>1.
__global__ __launch_bounds__(256, 3) void k_gemm1(
    const float* __restrict__ x, const float* __restrict__ W,
    const float* __restrict__ a_src, const float* __restrict__ a_dst,
    unsigned short* __restrict__ h_bf, float* __restrict__ ss, float* __restrict__ sd, int N){
  __shared__ unsigned short Wt[128 * 136];   // Wt[n][k], stride 136 (2-way bank alias: free)
  __shared__ unsigned short Xb[64 * 136];    // Xb[row][k], stride 136
  int t = threadIdx.x;
  int rb = blockIdx.x * 64;

  // stage W transposed as bf16: thread = (col n, k-half)
  {
    int n = t & 127, kh = (t >> 7) << 6;
    #pragma unroll
    for (int j = 0; j < 16; j++){
      int k0 = kh + j * 4;
      float w0 = W[(size_t)(k0 + 0) * 128 + n];
      float w1 = W[(size_t)(k0 + 1) * 128 + n];
      float w2 = W[(size_t)(k0 + 2) * 128 + n];
      float w3 = W[(size_t)(k0 + 3) * 128 + n];
      uint2 pk;
      pk.x = ((unsigned)f2bf(w1) << 16) | f2bf(w0);
      pk.y = ((unsigned)f2bf(w3) << 16) | f2bf(w2);
      *(uint2*)&Wt[n * 136 + k0] = pk;
    }
  }
  // stage X rows as bf16
  #pragma unroll
  for (int j = 0; j < 8; j++){
    int fi = j * 256 + t;           // 0..2047
    int row = fi >> 5, k4 = (fi & 31) * 4;
    int gr = rb + row;
    float4 v = make_float4(0.f, 0.f, 0.f, 0.f);
    if (gr < N) v = *(const float4*)&x[(size_t)gr * 128 + k4];
    uint2 pk;
    pk.x = ((unsigned)f2bf(v.y) << 16) | f2bf(v.x);
    pk.y = ((unsigned)f2bf(v.w) << 16) | f2bf(v.z);
    *(uint2*)&Xb[row * 136 + k4] = pk;
  }
  __syncthreads();

  int w = t >> 6, l = t & 63;
  int m = l & 15, quad = l >> 4;
  f32x4 acc[8];
  #pragma unroll
  for (int ct = 0; ct < 8; ct++) acc[ct] = (f32x4){0.f, 0.f, 0.f, 0.f};

  #pragma unroll
  for (int kc = 0; kc < 4; kc++){
    short8 a = *(const short8*)&Xb[(w * 16 + m) * 136 + kc * 32 + quad * 8];
    #pragma unroll
    for (int ct = 0; ct < 8; ct++){
      short8 b = *(const short8*)&Wt[(ct * 16 + m) * 136 + kc * 32 + quad * 8];
      acc[ct] = __builtin_amdgcn_mfma_f32_16x16x32_bf16(a, b, acc[ct], 0, 0, 0);
    }
  }

  float as[8], ad[8];
  #pragma unroll
  for (int ct = 0; ct < 8; ct++){ as[ct] = a_src[ct * 16 + m]; ad[ct] = a_dst[ct * 16 + m]; }

  #pragma unroll
  for (int reg = 0; reg < 4; reg++){
    int gr = rb + w * 16 + quad * 4 + reg;
    bool ok = gr < N;
    if (ok){
      #pragma unroll
      for (int ct = 0; ct < 8; ct++)
        h_bf[(size_t)gr * 128 + ct * 16 + m] = f2bf(acc[ct][reg]);
    }
    #pragma unroll
    for (int hh = 0; hh < 4; hh++){
      float ps = acc[2*hh][reg] * as[2*hh] + acc[2*hh+1][reg] * as[2*hh+1];
      float pd = acc[2*hh][reg] * ad[2*hh] + acc[2*hh+1][reg] * ad[2*hh+1];
      ps += __shfl_xor(ps, 1, 16); ps += __shfl_xor(ps, 2, 16);
      ps += __shfl_xor(ps, 4, 16); ps += __shfl_xor(ps, 8, 16);
      pd += __shfl_xor(pd, 1, 16); pd += __shfl_xor(pd, 2, 16);
      pd += __shfl_xor(pd, 4, 16); pd += __shfl_xor(pd, 8, 16);
      if (m == 0 && ok){ ss[(size_t)gr * 4 + hh] = ps; sd[(size_t)gr * 4 + hh] = pd; }
    }
  }
}

// ---------------- agg1: 1 wave per node; x8 edge unroll (8 gathers in flight) ----------------
__global__ __launch_bounds__(256) void k_agg1(
    const int* __restrict__ row_ptr, const int* __restrict__ csr_src,
    const float* __restrict__ ss, const float* __restrict__ sdst,
    const __hip_bfloat162* __restrict__ hb2,
    unsigned int* __restrict__ out1_bf, int N){
  int n = blockIdx.x * 4 + (threadIdx.x >> 6);
  if (n >= N) return;
  int l = threadIdx.x & 63;
  int hd = l >> 4;                 // this lane's head (channels 2l, 2l+1)
  float sdv = sdst[(size_t)n * 4 + hd];
  int j8 = l & 7, hh8 = (l >> 3) & 3;    // x8: lanes (mod 32) cover edge x head grid
  float sw8 = sdst[(size_t)n * 4 + hh8];
  int j4 = l & 3, hh4 = (l >> 2) & 3;    // x4 tail mapping
  float sw4 = sdst[(size_t)n * 4 + hh4];
  int beg = row_ptr[n], end = row_ptr[n + 1];
  float ax = 0.f, ay = 0.f, sw = 0.f;
  int e = beg;
  for (; e + 8 <= end; e += 8){
    int sj = csr_src[e + j8];
    float wv = __expf(lrelu(ss[(size_t)sj * 4 + hh8] + sw8));
    int s0 = __shfl(sj, 0, 8), s1 = __shfl(sj, 1, 8), s2 = __shfl(sj, 2, 8), s3 = __shfl(sj, 3, 8);
    int s4 = __shfl(sj, 4, 8), s5 = __shfl(sj, 5, 8), s6 = __shfl(sj, 6, 8), s7 = __shfl(sj, 7, 8);
    float w0 = __shfl(wv, hd * 8 + 0, 32), w1 = __shfl(wv, hd * 8 + 1, 32);
    float w2 = __shfl(wv, hd * 8 + 2, 32), w3 = __shfl(wv, hd * 8 + 3, 32);
    float w4 = __shfl(wv, hd * 8 + 4, 32), w5 = __shfl(wv, hd * 8 + 5, 32);
    float w6 = __shfl(wv, hd * 8 + 6, 32), w7 = __shfl(wv, hd * 8 + 7, 32);
    float2 v0 = __bfloat1622float2(hb2[(size_t)s0 * 64 + l]);
    float2 v1 = __bfloat1622float2(hb2[(size_t)s1 * 64 + l]);
    float2 v2 = __bfloat1622float2(hb2[(size_t)s2 * 64 + l]);
    float2 v3 = __bfloat1622float2(hb2[(size_t)s3 * 64 + l]);
    float2 v4 = __bfloat1622float2(hb2[(size_t)s4 * 64 + l]);
    float2 v5 = __bfloat1622float2(hb2[(size_t)s5 * 64 + l]);
    float2 v6 = __bfloat1622float2(hb2[(size_t)s6 * 64 + l]);
    float2 v7 = __bfloat1622float2(hb2[(size_t)s7 * 64 + l]);
    ax += w0*v0.x + w1*v1.x + w2*v2.x + w3*v3.x + w4*v4.x + w5*v5.x + w6*v6.x + w7*v7.x;
    ay += w0*v0.y + w1*v1.y + w2*v2.y + w3*v3.y + w4*v4.y + w5*v5.y + w6*v6.y + w7*v7.y;
    sw += w0 + w1 + w2 + w3 + w4 + w5 + w6 + w7;
  }
  for (; e + 4 <= end; e += 4){
    int sj = csr_src[e + j4];
    float wv = __expf(lrelu(ss[(size_t)sj * 4 + hh4] + sw4));
    int s0 = __shfl(sj, 0, 4), s1 = __shfl(sj, 1, 4);
    int s2 = __shfl(sj, 2, 4), s3 = __shfl(sj, 3, 4);
    float w0 = __shfl(wv, hd * 4 + 0, 16), w1 = __shfl(wv, hd * 4 + 1, 16);
    float w2 = __shfl(wv, hd * 4 + 2, 16), w3 = __shfl(wv, hd * 4 + 3, 16);
    float2 v0 = __bfloat1622float2(hb2[(size_t)s0 * 64 + l]);
    float2 v1 = __bfloat1622float2(hb2[(size_t)s1 * 64 + l]);
    float2 v2 = __bfloat1622float2(hb2[(size_t)s2 * 64 + l]);
    float2 v3 = __bfloat1622float2(hb2[(size_t)s3 * 64 + l]);
    ax += w0*v0.x + w1*v1.x + w2*v2.x + w3*v3.x;
    ay += w0*v0.y + w1*v1.y + w2*v2.y + w3*v3.y;
    sw += w0 + w1 + w2 + w3;
  }
  for (; e < end; e++){
    int s = csr_src[e];
    float w = __expf(lrelu(ss[(size_t)s * 4 + hd] + sdv));
    float2 v = __bfloat1622float2(hb2[(size_t)s * 64 + l]);
    ax += w*v.x; ay += w*v.y; sw += w;
  }
  float inv = 1.f / (sw + 1e-16f);
  unsigned int lo = f2bf(ax * inv), hi = f2bf(ay * inv);
  out1_bf[(size_t)n * 64 + l] = (hi << 16) | lo;
}

// ---------------- GEMM2: elu(out1_bf+b1)[N,128] @ W2[128,32] -> h2_bf[N,32], + s_src2/s_dst2[N]
__global__ __launch_bounds__(256) void k_gemm2(
    const unsigned int* __restrict__ out1_bf, const float* __restrict__ b1,
    const float* __restrict__ W2,
    const float* __restrict__ a_src, const float* __restrict__ a_dst,
    unsigned short* __restrict__ h2_bf, float* __restrict__ s_src2, float* __restrict__ s_dst2, int N){
  __shared__ __align__(16) float Wl[128 * 32];
  __shared__ __align__(16) float Xl[64 * 132];
  int t = threadIdx.x;
  int rb = blockIdx.x * 64;

  const float4* Wg4 = (const float4*)W2;
  float4* Wl4 = (float4*)Wl;
  #pragma unroll
  for (int j = 0; j < 4; j++) Wl4[j * 256 + t] = Wg4[j * 256 + t];

  // out1_bf row = 64 uints; q covers channels q*8..q*8+7 -> uint offset q*4
  #pragma unroll
  for (int j = 0; j < 4; j++){
    int fi = j * 256 + t;               // 0..1023
    int row = fi >> 4, q = fi & 15;     // q: 8-channel group
    int gr = rb + row;
    float v[8] = {0.f,0.f,0.f,0.f,0.f,0.f,0.f,0.f};
    if (gr < N){
      uint4 u = *(const uint4*)&out1_bf[(size_t)gr * 64 + q * 4];
      float4 bva = *(const float4*)&b1[q * 8];
      float4 bvb = *(const float4*)&b1[q * 8 + 4];
      v[0] = elu_f(bf2f((unsigned short)(u.x & 0xffff)) + bva.x);
      v[1] = elu_f(bf2f((unsigned short)(u.x >> 16))    + bva.y);
      v[2] = elu_f(bf2f((unsigned short)(u.y & 0xffff)) + bva.z);
      v[3] = elu_f(bf2f((unsigned short)(u.y >> 16))    + bva.w);
      v[4] = elu_f(bf2f((unsigned short)(u.z & 0xffff)) + bvb.x);
      v[5] = elu_f(bf2f((unsigned short)(u.z >> 16))    + bvb.y);
      v[6] = elu_f(bf2f((unsigned short)(u.w & 0xffff)) + bvb.z);
      v[7] = elu_f(bf2f((unsigned short)(u.w >> 16))    + bvb.w);
    }
    #pragma unroll
    for (int i = 0; i < 8; i++) Xl[row * 132 + q * 8 + i] = v[i];
  }
  __syncthreads();

  int cg = t & 7, rg = t >> 3;
  int c0 = cg * 4, r0 = rg * 2;
  float acc[2][4] = {};

  #pragma unroll 8
  for (int k = 0; k < 128; k++){
    float a0 = Xl[r0 * 132 + k];
    float a1 = Xl[(r0 + 1) * 132 + k];
    float4 b = *(float4*)&Wl[k * 32 + c0];
    acc[0][0] += a0 * b.x; acc[0][1] += a0 * b.y; acc[0][2] += a0 * b.z; acc[0][3] += a0 * b.w;
    acc[1][0] += a1 * b.x; acc[1][1] += a1 * b.y; acc[1][2] += a1 * b.z; acc[1][3] += a1 * b.w;
  }

  float as[4], ad[4];
  #pragma unroll
  for (int j = 0; j < 4; j++){ as[j] = a_src[c0 + j]; ad[j] = a_dst[c0 + j]; }
  #pragma unroll
  for (int i = 0; i < 2; i++){
    int row = rb + r0 + i;
    if (row < N){
      ushort4 o;
      o.x = f2bf(acc[i][0]); o.y = f2bf(acc[i][1]); o.z = f2bf(acc[i][2]); o.w = f2bf(acc[i][3]);
      *(ushort4*)&h2_bf[(size_t)row * 32 + c0] = o;
    }
    float ps = 0.f, pd = 0.f;
    #pragma unroll
    for (int j = 0; j < 4; j++){ ps += acc[i][j] * as[j]; pd += acc[i][j] * ad[j]; }
    ps += __shfl_xor(ps, 1, 8); ps += __shfl_xor(ps, 2, 8); ps += __shfl_xor(ps, 4, 8);
    pd += __shfl_xor(pd, 1, 8); pd += __shfl_xor(pd, 2, 8); pd += __shfl_xor(pd, 4, 8);
    if ((t & 7) == 0 && row < N){ s_src2[row] = ps; s_dst2[row] = pd; }
  }
}

// ---------------- agg2: 8 nodes/block (32 ch each), fused weights (1 exp per lane per 4 edges)
__global__ __launch_bounds__(256) void k_agg2(
    const int* __restrict__ row_ptr, const int* __restrict__ csr_src,
    const float* __restrict__ ss2, const float* __restrict__ sd2,
    const unsigned short* __restrict__ h2bf, const float* __restrict__ b2,
    float* __restrict__ out, int N){
  int n = blockIdx.x * 8 + (threadIdx.x >> 5);
  if (n >= N) return;
  int c = threadIdx.x & 31;
  float sdv = sd2[n];
  int beg = row_ptr[n], end = row_ptr[n + 1];
  float acc = 0.f, sw = 0.f;
  int e = beg;
  for (; e + 4 <= end; e += 4){
    int s0 = csr_src[e], s1 = csr_src[e+1], s2 = csr_src[e+2], s3 = csr_src[e+3];
    int sj = csr_src[e + (c & 3)];
    float wv = __expf(lrelu(ss2[sj] + sdv));
    float w0 = __shfl(wv, 0, 4), w1 = __shfl(wv, 1, 4);
    float w2 = __shfl(wv, 2, 4), w3 = __shfl(wv, 3, 4);
    float v0 = bf2f(h2bf[(size_t)s0 * 32 + c]);
    float v1 = bf2f(h2bf[(size_t)s1 * 32 + c]);
    float v2 = bf2f(h2bf[(size_t)s2 * 32 + c]);
    float v3 = bf2f(h2bf[(size_t)s3 * 32 + c]);
    acc += w0*v0 + w1*v1 + w2*v2 + w3*v3;
    sw += w0 + w1 + w2 + w3;
  }
  for (; e < end; e++){
    int s = csr_src[e];
    float w = __expf(lrelu(ss2[s] + sdv));
    acc += w * bf2f(h2bf[(size_t)s * 32 + c]);
    sw += w;
  }
  out[(size_t)n * 32 + c] = acc / (sw + 1e-16f) + b2[c];
}

extern "C" void kernel_launch(void* const* d_in, const int* in_sizes, int n_in,
                              void* d_out, int out_size, void* d_ws, size_t ws_size,
                              hipStream_t stream) {
  const float* x      = (const float*)d_in[0];
  const int*   ei     = (const int*)  d_in[1];
  const float* W1     = (const float*)d_in[2];
  const float* a_src1 = (const float*)d_in[3];
  const float* a_dst1 = (const float*)d_in[4];
  const float* b1     = (const float*)d_in[5];
  const float* W2     = (const float*)d_in[6];
  const float* a_src2 = (const float*)d_in[7];
  const float* a_dst2 = (const float*)d_in[8];
  const float* b2     = (const float*)d_in[9];
  float* out = (float*)d_out;

  int N = in_sizes[0] / 128;
  int E = in_sizes[1] / 2;
  const int* srcp = ei;
  const int* dstp = ei + E;
  int total = E + N;
  int NBK = (N + 511) >> 9;       // buckets of 512 nodes

  char* p = (char*)d_ws;
  auto alloc = [&](size_t bytes) -> void* {
    void* r = (void*)p; p += (bytes + 255) & ~(size_t)255; return r;
  };
  unsigned short* h_bf    = (unsigned short*)alloc((size_t)N * 128 * 2);
  unsigned int*   out1_bf = (unsigned int*)alloc((size_t)N * 64 * 4);   // 128 bf16/row packed as 64 uint
  unsigned short* h2_bf   = (unsigned short*)alloc((size_t)N * 32 * 2);
  float* ss1  = (float*)alloc((size_t)N * 4 * 4);
  float* sd1  = (float*)alloc((size_t)N * 4 * 4);
  float* ss2  = (float*)alloc((size_t)N * 4);
  float* sd2  = (float*)alloc((size_t)N * 4);
  int* rowp   = (int*)alloc((size_t)(N + 1) * 4);
  int* csr    = (int*)alloc((size_t)total * 4);
  int* bbase  = (int*)alloc(256 * 4);
  int* gcur   = (int*)alloc(256 * 4);
  // ebuf (bucket staging, 196*9216*8 = 14.5 MB) aliases out1_bf (25.6 MB):
  // lifetimes disjoint (ebuf: binA..csrB2; out1_bf: agg1..gemm2)
  int2* ebuf  = (int2*)out1_bf;
  (void)ws_size; (void)n_in; (void)out_size;

  hipMemsetAsync(gcur, 0, 256 * 4, stream);
  k_binA<<<(E + 4095) / 4096, 256, 0, stream>>>(srcp, dstp, E, gcur, ebuf);
  k_bscan<<<1, 256, 0, stream>>>(gcur, bbase, rowp, N, NBK, total);
  k_csrB2<<<NBK, 256, 0, stream>>>(ebuf, gcur, bbase, rowp, csr, N);

  k_gemm1<<<(N + 63) / 64, 256, 0, stream>>>(x, W1, a_src1, a_dst1, h_bf, ss1, sd1, N);
  k_agg1<<<(N + 3) / 4, 256, 0, stream>>>(rowp, csr, ss1, sd1, (const __hip_bfloat162*)h_bf, out1_bf, N);
  k_gemm2<<<(N + 63) / 64, 256, 0, stream>>>(out1_bf, b1, W2, a_src2, a_dst2, h2_bf, ss2, sd2, N);
  k_agg2<<<(N + 7) / 8, 256, 0, stream>>>(rowp, csr, ss2, sd2, h2_bf, b2, out, N);
}

// Round 10
// 310.447 us; speedup vs baseline: 6.1536x; 1.0668x over previous
//
#include <hip/hip_runtime.h>
#include <hip/hip_bf16.h>

#define NEG 0.2f
#define BK_SHIFT 9       // 512 nodes per bucket
#define BK_CAP 9216      // slots per bucket (mean ~8192, sigma ~90 -> 11 sigma headroom)

typedef short short8 __attribute__((ext_vector_type(8)));   // 8 bf16 (4 VGPRs)
typedef float f32x4 __attribute__((ext_vector_type(4)));

__device__ __forceinline__ float lrelu(float x){ return x > 0.f ? x : NEG * x; }
__device__ __forceinline__ float elu_f(float x){ return x > 0.f ? x : expm1f(x); }
__device__ __forceinline__ unsigned short f2bf(float f){
  unsigned int u = __float_as_uint(f);
  unsigned int r = u + 0x7fffu + ((u >> 16) & 1u);   // round-to-nearest-even
  return (unsigned short)(r >> 16);
}
__device__ __forceinline__ float bf2f(unsigned short u){
  return __uint_as_float(((unsigned int)u) << 16);
}

// ---------------- CSR build ----------------
// Phase A: bin edges into bucket-major ebuf (contiguous runs -> no write-allocate blowup)
__global__ __launch_bounds__(512) void k_binA(
    const int* __restrict__ src, const int* __restrict__ dst, int E,
    int* __restrict__ gcursor, int2* __restrict__ ebuf){
  __shared__ int hist[256];
  __shared__ int base[256];
  int t = threadIdx.x;
  if (t < 256) hist[t] = 0;
  __syncthreads();
  int e0 = blockIdx.x * 4096;
  for (int j = 0; j < 8; j++){
    int e = e0 + j * 512 + t;
    if (e < E) atomicAdd(&hist[dst[e] >> BK_SHIFT], 1);
  }
  __syncthreads();
  if (t < 256){
    int cnt = hist[t];
    if (cnt > 0) base[t] = atomicAdd(&gcursor[t], cnt);
    hist[t] = 0;                 // reuse as local placement cursor
  }
  __syncthreads();
  for (int j = 0; j < 8; j++){
    int e = e0 + j * 512 + t;
    if (e < E){
      int d = dst[e]; int b = d >> BK_SHIFT;
      int loc = atomicAdd(&hist[b], 1);
      ebuf[(size_t)b * BK_CAP + base[b] + loc] = make_int2(src[e], d);
    }
  }
}

// csrC: per-bucket CSR build, 1024 threads. Inlines the bucket-base scan (each block
// redundantly scans gcount[0..NBK), 196 ints - cheap), then deg-histogram + LDS scan
// -> rowp, then placement replay (ebuf L2-warm). Self-loop at rowp[n]+deg[n].
__global__ __launch_bounds__(1024) void k_csrC(
    const int2* __restrict__ ebuf, const int* __restrict__ gcount,
    int* __restrict__ rowp, int* __restrict__ csr, int N, int NBK, int total){
  __shared__ int hist[512];
  __shared__ int psum[256];
  __shared__ int bsum[256];
  int b = blockIdx.x, t = threadIdx.x;
  int nbase = b << BK_SHIFT;
  int cnt = gcount[b];
  const int2* eb = ebuf + (size_t)b * BK_CAP;
  if (t < 512) hist[t] = 0;
  int bv = 0;
  if (t < 256){
    int nodes = 0;
    if (t < NBK){ int nb = N - (t << BK_SHIFT); nodes = nb > 512 ? 512 : nb; bv = gcount[t] + nodes; }
    bsum[t] = bv;
  }
  __syncthreads();
  for (int off = 1; off < 256; off <<= 1){
    int x = (t >= off && t < 256) ? bsum[t - off] : 0;
    __syncthreads();
    if (t < 256) bsum[t] += x;
    __syncthreads();
  }
  for (int i = t; i < cnt; i += 1024)
    atomicAdd(&hist[eb[i].y - nbase], 1);
  __syncthreads();
  int v0 = 0, v1 = 0, ps = 0;
  if (t < 256){ v0 = hist[2 * t]; v1 = hist[2 * t + 1]; ps = v0 + v1; psum[t] = ps; }
  __syncthreads();
  for (int off = 1; off < 256; off <<= 1){
    int x = (t >= off && t < 256) ? psum[t - off] : 0;
    __syncthreads();
    if (t < 256) psum[t] += x;
    __syncthreads();
  }
  if (t < 256){
    int eo = psum[t] - ps;               // exclusive deg-sum at node 2t
    int bb = (b == 0) ? 0 : bsum[b - 1];
    int n0 = 2 * t, n1 = 2 * t + 1;
    int r0 = bb + eo + n0;               // +n0: one self-loop slot per prior node
    int r1 = bb + eo + v0 + n1;
    if (nbase + n0 < N) rowp[nbase + n0] = r0;
    if (nbase + n1 < N) rowp[nbase + n1] = r1;
    hist[n0] = r0; hist[n1] = r1;        // reuse as cursors
  }
  if (b == 0 && t == 0) rowp[N] = total;
  __syncthreads();
  for (int i = t; i < cnt; i += 1024){
    int2 e = eb[i];
    int pos = atomicAdd(&hist[e.y - nbase], 1);
    csr[pos] = e.x;
  }
  __syncthreads();
  if (t < 256){
    int n0 = 2 * t, n1 = 2 * t + 1;
    if (nbase + n0 < N) csr[hist[n0]] = nbase + n0;
    if (nbase + n1 < N) csr[hist[n1]] = nbase + n1;
  }
}

// ---------------- packW: W1 -> bf16 transposed (Wp[n][k]), done once ----------------
__global__ __launch_bounds__(128) void k_packW(
    const float* __restrict__ W, unsigned short* __restrict__ Wp){
  int n = blockIdx.x, k = threadIdx.x;
  Wp[n * 128 + k] = f2bf(W[(size_t)k * 128 + n]);
}

// ---------------- GEMM1 (MFMA bf16): x[N,128] @ W[128,128] -> h_bf[N,128], + ss1/sd1 fused
// 64 rows x 128 cols / block; 4 waves, each 16 rows x 128 cols as 8 col-tiles of 16x16x32 MFMA.
// D layout: row = quad*4+reg, col = ct*16 + (lane&15).
__global__ __launch_bounds__(256, 3) void k_gemm1(
    const float* __restrict__ x, const unsigned short* __restrict__ Wp,
    const float* __restrict__ a_src, const float* __restrict__ a_dst,
    unsigned short* __restrict__ h_bf, float* __restrict__ ss, float* __restrict__ sd, int N){
  __shared__ unsigned short Wt[128 * 136];   // Wt[n][k], stride 136 (2-way bank alias: free)
  __shared__ unsigned short Xb[64 * 136];    // Xb[row][k], stride 136
  int t = threadIdx.x;
  int rb = blockIdx.x * 64;

  // stage pre-packed W' (32 KB) via uint4: 2048 items = 128 cols x 16 chunks of 8 shorts
  // (R9 bug: j<4 with ch&7 only filled k=0..63 -> MFMA ate poison LDS -> NaN)
  #pragma unroll
  for (int j = 0; j < 8; j++){
    int fi = j * 256 + t;
    int n = fi >> 4, ch = fi & 15;
    *(uint4*)&Wt[n * 136 + ch * 8] = *(const uint4*)&Wp[n * 128 + ch * 8];
  }
  // stage X rows as bf16
  #pragma unroll
  for (int j = 0; j < 8; j++){
    int fi = j * 256 + t;           // 0..2047
    int row = fi >> 5, k4 = (fi & 31) * 4;
    int gr = rb + row;
    float4 v = make_float4(0.f, 0.f, 0.f, 0.f);
    if (gr < N) v = *(const float4*)&x[(size_t)gr * 128 + k4];
    uint2 pk;
    pk.x = ((unsigned)f2bf(v.y) << 16) | f2bf(v.x);
    pk.y = ((unsigned)f2bf(v.w) << 16) | f2bf(v.z);
    *(uint2*)&Xb[row * 136 + k4] = pk;
  }
  __syncthreads();

  int w = t >> 6, l = t & 63;
  int m = l & 15, quad = l >> 4;
  f32x4 acc[8];
  #pragma unroll
  for (int ct = 0; ct < 8; ct++) acc[ct] = (f32x4){0.f, 0.f, 0.f, 0.f};

  #pragma unroll
  for (int kc = 0; kc < 4; kc++){
    short8 a = *(const short8*)&Xb[(w * 16 + m) * 136 + kc * 32 + quad * 8];
    #pragma unroll
    for (int ct = 0; ct < 8; ct++){
      short8 b = *(const short8*)&Wt[(ct * 16 + m) * 136 + kc * 32 + quad * 8];
      acc[ct] = __builtin_amdgcn_mfma_f32_16x16x32_bf16(a, b, acc[ct], 0, 0, 0);
    }
  }

  float as[8], ad[8];
  #pragma unroll
  for (int ct = 0; ct < 8; ct++){ as[ct] = a_src[ct * 16 + m]; ad[ct] = a_dst[ct * 16 + m]; }

  #pragma unroll
  for (int reg = 0; reg < 4; reg++){
    int gr = rb + w * 16 + quad * 4 + reg;
    bool ok = gr < N;
    if (ok){
      #pragma unroll
      for (int ct = 0; ct < 8; ct++)
        h_bf[(size_t)gr * 128 + ct * 16 + m] = f2bf(acc[ct][reg]);
    }
    #pragma unroll
    for (int hh = 0; hh < 4; hh++){
      float ps = acc[2*hh][reg] * as[2*hh] + acc[2*hh+1][reg] * as[2*hh+1];
      float pd = acc[2*hh][reg] * ad[2*hh] + acc[2*hh+1][reg] * ad[2*hh+1];
      ps += __shfl_xor(ps, 1, 16); ps += __shfl_xor(ps, 2, 16);
      ps += __shfl_xor(ps, 4, 16); ps += __shfl_xor(ps, 8, 16);
      pd += __shfl_xor(pd, 1, 16); pd += __shfl_xor(pd, 2, 16);
      pd += __shfl_xor(pd, 4, 16); pd += __shfl_xor(pd, 8, 16);
      if (m == 0 && ok){ ss[(size_t)gr * 4 + hh] = ps; sd[(size_t)gr * 4 + hh] = pd; }
    }
  }
}

// ---------------- agg1: 1 wave per node; x8 edge unroll (8 gathers in flight) ----------------
__global__ __launch_bounds__(256) void k_agg1(
    const int* __restrict__ row_ptr, const int* __restrict__ csr_src,
    const float* __restrict__ ss, const float* __restrict__ sdst,
    const __hip_bfloat162* __restrict__ hb2,
    unsigned int* __restrict__ out1_bf, int N){
  int n = blockIdx.x * 4 + (threadIdx.x >> 6);
  if (n >= N) return;
  int l = threadIdx.x & 63;
  int hd = l >> 4;                 // this lane's head (channels 2l, 2l+1)
  float sdv = sdst[(size_t)n * 4 + hd];
  int j8 = l & 7, hh8 = (l >> 3) & 3;    // x8: lanes (mod 32) cover edge x head grid
  float sw8 = sdst[(size_t)n * 4 + hh8];
  int j4 = l & 3, hh4 = (l >> 2) & 3;    // x4 tail mapping
  float sw4 = sdst[(size_t)n * 4 + hh4];
  int beg = row_ptr[n], end = row_ptr[n + 1];
  float ax = 0.f, ay = 0.f, sw = 0.f;
  int e = beg;
  for (; e + 8 <= end; e += 8){
    int sj = csr_src[e + j8];
    float wv = __expf(lrelu(ss[(size_t)sj * 4 + hh8] + sw8));
    int s0 = __shfl(sj, 0, 8), s1 = __shfl(sj, 1, 8), s2 = __shfl(sj, 2, 8), s3 = __shfl(sj, 3, 8);
    int s4 = __shfl(sj, 4, 8), s5 = __shfl(sj, 5, 8), s6 = __shfl(sj, 6, 8), s7 = __shfl(sj, 7, 8);
    float w0 = __shfl(wv, hd * 8 + 0, 32), w1 = __shfl(wv, hd * 8 + 1, 32);
    float w2 = __shfl(wv, hd * 8 + 2, 32), w3 = __shfl(wv, hd * 8 + 3, 32);
    float w4 = __shfl(wv, hd * 8 + 4, 32), w5 = __shfl(wv, hd * 8 + 5, 32);
    float w6 = __shfl(wv, hd * 8 + 6, 32), w7 = __shfl(wv, hd * 8 + 7, 32);
    float2 v0 = __bfloat1622float2(hb2[(size_t)s0 * 64 + l]);
    float2 v1 = __bfloat1622float2(hb2[(size_t)s1 * 64 + l]);
    float2 v2 = __bfloat1622float2(hb2[(size_t)s2 * 64 + l]);
    float2 v3 = __bfloat1622float2(hb2[(size_t)s3 * 64 + l]);
    float2 v4 = __bfloat1622float2(hb2[(size_t)s4 * 64 + l]);
    float2 v5 = __bfloat1622float2(hb2[(size_t)s5 * 64 + l]);
    float2 v6 = __bfloat1622float2(hb2[(size_t)s6 * 64 + l]);
    float2 v7 = __bfloat1622float2(hb2[(size_t)s7 * 64 + l]);
    ax += w0*v0.x + w1*v1.x + w2*v2.x + w3*v3.x + w4*v4.x + w5*v5.x + w6*v6.x + w7*v7.x;
    ay += w0*v0.y + w1*v1.y + w2*v2.y + w3*v3.y + w4*v4.y + w5*v5.y + w6*v6.y + w7*v7.y;
    sw += w0 + w1 + w2 + w3 + w4 + w5 + w6 + w7;
  }
  for (; e + 4 <= end; e += 4){
    int sj = csr_src[e + j4];
    float wv = __expf(lrelu(ss[(size_t)sj * 4 + hh4] + sw4));
    int s0 = __shfl(sj, 0, 4), s1 = __shfl(sj, 1, 4);
    int s2 = __shfl(sj, 2, 4), s3 = __shfl(sj, 3, 4);
    float w0 = __shfl(wv, hd * 4 + 0, 16), w1 = __shfl(wv, hd * 4 + 1, 16);
    float w2 = __shfl(wv, hd * 4 + 2, 16), w3 = __shfl(wv, hd * 4 + 3, 16);
    float2 v0 = __bfloat1622float2(hb2[(size_t)s0 * 64 + l]);
    float2 v1 = __bfloat1622float2(hb2[(size_t)s1 * 64 + l]);
    float2 v2 = __bfloat1622float2(hb2[(size_t)s2 * 64 + l]);
    float2 v3 = __bfloat1622float2(hb2[(size_t)s3 * 64 + l]);
    ax += w0*v0.x + w1*v1.x + w2*v2.x + w3*v3.x;
    ay += w0*v0.y + w1*v1.y + w2*v2.y + w3*v3.y;
    sw += w0 + w1 + w2 + w3;
  }
  for (; e < end; e++){
    int s = csr_src[e];
    float w = __expf(lrelu(ss[(size_t)s * 4 + hd] + sdv));
    float2 v = __bfloat1622float2(hb2[(size_t)s * 64 + l]);
    ax += w*v.x; ay += w*v.y; sw += w;
  }
  float inv = 1.f / (sw + 1e-16f);
  unsigned int lo = f2bf(ax * inv), hi = f2bf(ay * inv);
  out1_bf[(size_t)n * 64 + l] = (hi << 16) | lo;
}

// ---------------- GEMM2: elu(out1_bf+b1)[N,128] @ W2[128,32] -> h2_bf[N,32], + s_src2/s_dst2[N]
__global__ __launch_bounds__(256) void k_gemm2(
    const unsigned int* __restrict__ out1_bf, const float* __restrict__ b1,
    const float* __restrict__ W2,
    const float* __restrict__ a_src, const float* __restrict__ a_dst,
    unsigned short* __restrict__ h2_bf, float* __restrict__ s_src2, float* __restrict__ s_dst2, int N){
  __shared__ __align__(16) float Wl[128 * 32];
  __shared__ __align__(16) float Xl[64 * 132];
  int t = threadIdx.x;
  int rb = blockIdx.x * 64;

  const float4* Wg4 = (const float4*)W2;
  float4* Wl4 = (float4*)Wl;
  #pragma unroll
  for (int j = 0; j < 4; j++) Wl4[j * 256 + t] = Wg4[j * 256 + t];

  // out1_bf row = 64 uints; q covers channels q*8..q*8+7 -> uint offset q*4
  #pragma unroll
  for (int j = 0; j < 4; j++){
    int fi = j * 256 + t;               // 0..1023
    int row = fi >> 4, q = fi & 15;     // q: 8-channel group
    int gr = rb + row;
    float v[8] = {0.f,0.f,0.f,0.f,0.f,0.f,0.f,0.f};
    if (gr < N){
      uint4 u = *(const uint4*)&out1_bf[(size_t)gr * 64 + q * 4];
      float4 bva = *(const float4*)&b1[q * 8];
      float4 bvb = *(const float4*)&b1[q * 8 + 4];
      v[0] = elu_f(bf2f((unsigned short)(u.x & 0xffff)) + bva.x);
      v[1] = elu_f(bf2f((unsigned short)(u.x >> 16))    + bva.y);
      v[2] = elu_f(bf2f((unsigned short)(u.y & 0xffff)) + bva.z);
      v[3] = elu_f(bf2f((unsigned short)(u.y >> 16))    + bva.w);
      v[4] = elu_f(bf2f((unsigned short)(u.z & 0xffff)) + bvb.x);
      v[5] = elu_f(bf2f((unsigned short)(u.z >> 16))    + bvb.y);
      v[6] = elu_f(bf2f((unsigned short)(u.w & 0xffff)) + bvb.z);
      v[7] = elu_f(bf2f((unsigned short)(u.w >> 16))    + bvb.w);
    }
    #pragma unroll
    for (int i = 0; i < 8; i++) Xl[row * 132 + q * 8 + i] = v[i];
  }
  __syncthreads();

  int cg = t & 7, rg = t >> 3;
  int c0 = cg * 4, r0 = rg * 2;
  float acc[2][4] = {};

  #pragma unroll 8
  for (int k = 0; k < 128; k++){
    float a0 = Xl[r0 * 132 + k];
    float a1 = Xl[(r0 + 1) * 132 + k];
    float4 b = *(float4*)&Wl[k * 32 + c0];
    acc[0][0] += a0 * b.x; acc[0][1] += a0 * b.y; acc[0][2] += a0 * b.z; acc[0][3] += a0 * b.w;
    acc[1][0] += a1 * b.x; acc[1][1] += a1 * b.y; acc[1][2] += a1 * b.z; acc[1][3] += a1 * b.w;
  }

  float as[4], ad[4];
  #pragma unroll
  for (int j = 0; j < 4; j++){ as[j] = a_src[c0 + j]; ad[j] = a_dst[c0 + j]; }
  #pragma unroll
  for (int i = 0; i < 2; i++){
    int row = rb + r0 + i;
    if (row < N){
      ushort4 o;
      o.x = f2bf(acc[i][0]); o.y = f2bf(acc[i][1]); o.z = f2bf(acc[i][2]); o.w = f2bf(acc[i][3]);
      *(ushort4*)&h2_bf[(size_t)row * 32 + c0] = o;
    }
    float ps = 0.f, pd = 0.f;
    #pragma unroll
    for (int j = 0; j < 4; j++){ ps += acc[i][j] * as[j]; pd += acc[i][j] * ad[j]; }
    ps += __shfl_xor(ps, 1, 8); ps += __shfl_xor(ps, 2, 8); ps += __shfl_xor(ps, 4, 8);
    pd += __shfl_xor(pd, 1, 8); pd += __shfl_xor(pd, 2, 8); pd += __shfl_xor(pd, 4, 8);
    if ((t & 7) == 0 && row < N){ s_src2[row] = ps; s_dst2[row] = pd; }
  }
}

// ---------------- agg2: 8 nodes/block (32 ch each), x8 unroll, fused weights ----------------
__global__ __launch_bounds__(256) void k_agg2(
    const int* __restrict__ row_ptr, const int* __restrict__ csr_src,
    const float* __restrict__ ss2, const float* __restrict__ sd2,
    const unsigned short* __restrict__ h2bf, const float* __restrict__ b2,
    float* __restrict__ out, int N){
  int n = blockIdx.x * 8 + (threadIdx.x >> 5);
  if (n >= N) return;
  int c = threadIdx.x & 31;
  float sdv = sd2[n];
  int beg = row_ptr[n], end = row_ptr[n + 1];
  float acc = 0.f, sw = 0.f;
  int e = beg;
  int j8 = c & 7;
  for (; e + 8 <= end; e += 8){
    int sj = csr_src[e + j8];
    float wv = __expf(lrelu(ss2[sj] + sdv));
    int s0 = __shfl(sj, 0, 8), s1 = __shfl(sj, 1, 8), s2 = __shfl(sj, 2, 8), s3 = __shfl(sj, 3, 8);
    int s4 = __shfl(sj, 4, 8), s5 = __shfl(sj, 5, 8), s6 = __shfl(sj, 6, 8), s7 = __shfl(sj, 7, 8);
    float w0 = __shfl(wv, 0, 8), w1 = __shfl(wv, 1, 8), w2 = __shfl(wv, 2, 8), w3 = __shfl(wv, 3, 8);
    float w4 = __shfl(wv, 4, 8), w5 = __shfl(wv, 5, 8), w6 = __shfl(wv, 6, 8), w7 = __shfl(wv, 7, 8);
    float v0 = bf2f(h2bf[(size_t)s0 * 32 + c]);
    float v1 = bf2f(h2bf[(size_t)s1 * 32 + c]);
    float v2 = bf2f(h2bf[(size_t)s2 * 32 + c]);
    float v3 = bf2f(h2bf[(size_t)s3 * 32 + c]);
    float v4 = bf2f(h2bf[(size_t)s4 * 32 + c]);
    float v5 = bf2f(h2bf[(size_t)s5 * 32 + c]);
    float v6 = bf2f(h2bf[(size_t)s6 * 32 + c]);
    float v7 = bf2f(h2bf[(size_t)s7 * 32 + c]);
    acc += w0*v0 + w1*v1 + w2*v2 + w3*v3 + w4*v4 + w5*v5 + w6*v6 + w7*v7;
    sw += w0 + w1 + w2 + w3 + w4 + w5 + w6 + w7;
  }
  for (; e + 4 <= end; e += 4){
    int s0 = csr_src[e], s1 = csr_src[e+1], s2 = csr_src[e+2], s3 = csr_src[e+3];
    int sj = csr_src[e + (c & 3)];
    float wv = __expf(lrelu(ss2[sj] + sdv));
    float w0 = __shfl(wv, 0, 4), w1 = __shfl(wv, 1, 4);
    float w2 = __shfl(wv, 2, 4), w3 = __shfl(wv, 3, 4);
    float v0 = bf2f(h2bf[(size_t)s0 * 32 + c]);
    float v1 = bf2f(h2bf[(size_t)s1 * 32 + c]);
    float v2 = bf2f(h2bf[(size_t)s2 * 32 + c]);
    float v3 = bf2f(h2bf[(size_t)s3 * 32 + c]);
    acc += w0*v0 + w1*v1 + w2*v2 + w3*v3;
    sw += w0 + w1 + w2 + w3;
  }
  for (; e < end; e++){
    int s = csr_src[e];
    float w = __expf(lrelu(ss2[s] + sdv));
    acc += w * bf2f(h2bf[(size_t)s * 32 + c]);
    sw += w;
  }
  out[(size_t)n * 32 + c] = acc / (sw + 1e-16f) + b2[c];
}

extern "C" void kernel_launch(void* const* d_in, const int* in_sizes, int n_in,
                              void* d_out, int out_size, void* d_ws, size_t ws_size,
                              hipStream_t stream) {
  const float* x      = (const float*)d_in[0];
  const int*   ei     = (const int*)  d_in[1];
  const float* W1     = (const float*)d_in[2];
  const float* a_src1 = (const float*)d_in[3];
  const float* a_dst1 = (const float*)d_in[4];
  const float* b1     = (const float*)d_in[5];
  const float* W2     = (const float*)d_in[6];
  const float* a_src2 = (const float*)d_in[7];
  const float* a_dst2 = (const float*)d_in[8];
  const float* b2     = (const float*)d_in[9];
  float* out = (float*)d_out;

  int N = in_sizes[0] / 128;
  int E = in_sizes[1] / 2;
  const int* srcp = ei;
  const int* dstp = ei + E;
  int total = E + N;
  int NBK = (N + 511) >> 9;       // buckets of 512 nodes

  char* p = (char*)d_ws;
  auto alloc = [&](size_t bytes) -> void* {
    void* r = (void*)p; p += (bytes + 255) & ~(size_t)255; return r;
  };
  unsigned short* h_bf    = (unsigned short*)alloc((size_t)N * 128 * 2);
  unsigned int*   out1_bf = (unsigned int*)alloc((size_t)N * 64 * 4);   // 128 bf16/row packed as 64 uint
  unsigned short* h2_bf   = (unsigned short*)alloc((size_t)N * 32 * 2);
  unsigned short* Wp      = (unsigned short*)alloc(128 * 128 * 2);
  float* ss1  = (float*)alloc((size_t)N * 4 * 4);
  float* sd1  = (float*)alloc((size_t)N * 4 * 4);
  float* ss2  = (float*)alloc((size_t)N * 4);
  float* sd2  = (float*)alloc((size_t)N * 4);
  int* rowp   = (int*)alloc((size_t)(N + 1) * 4);
  int* csr    = (int*)alloc((size_t)total * 4);
  int* gcur   = (int*)alloc(256 * 4);
  // ebuf (bucket staging, 196*9216*8 = 14.5 MB) aliases out1_bf (25.6 MB):
  // lifetimes disjoint (ebuf: binA..csrC; out1_bf: agg1..gemm2)
  int2* ebuf  = (int2*)out1_bf;
  (void)ws_size; (void)n_in; (void)out_size;

  hipMemsetAsync(gcur, 0, 256 * 4, stream);
  k_binA<<<(E + 4095) / 4096, 512, 0, stream>>>(srcp, dstp, E, gcur, ebuf);
  k_csrC<<<NBK, 1024, 0, stream>>>(ebuf, gcur, rowp, csr, N, NBK, total);

  k_packW<<<128, 128, 0, stream>>>(W1, Wp);
  k_gemm1<<<(N + 63) / 64, 256, 0, stream>>>(x, Wp, a_src1, a_dst1, h_bf, ss1, sd1, N);
  k_agg1<<<(N + 3) / 4, 256, 0, stream>>>(rowp, csr, ss1, sd1, (const __hip_bfloat162*)h_bf, out1_bf, N);
  k_gemm2<<<(N + 63) / 64, 256, 0, stream>>>(out1_bf, b1, W2, a_src2, a_dst2, h2_bf, ss2, sd2, N);
  k_agg2<<<(N + 7) / 8, 256, 0, stream>>>(rowp, csr, ss2, sd2, h2_bf, b2, out, N);
}